// Round 8
// baseline (5736.436 us; speedup 1.0000x reference)
//
#include <hip/hip_runtime.h>

#define NB 2
#define NN 16384
#define NC 256
#define NPp 2048
#define NSs 32
#define NH 4
#define HDh 64
#define NL 2
#define NDFF 512
#define LFv (NPp*NSs)
#define LNEPS 1e-5f
#define NBLK 256
#define NTHR 1024
#define NW 16

typedef short s16x8 __attribute__((ext_vector_type(8)));
typedef float f32x4 __attribute__((ext_vector_type(4)));
typedef float f32x2 __attribute__((ext_vector_type(2)));
typedef unsigned short u16;
typedef unsigned long long u64;

struct CtlBlock { int prog[2]; int ctr1; int ctr2; int bar; };

__device__ __forceinline__ u16 f2bf(float f){
  unsigned u = __float_as_uint(f);
  u += 0x7fffu + ((u>>16)&1u);
  return (u16)(u>>16);
}

__device__ __forceinline__ f32x4 mfma16(s16x8 a, s16x8 b, f32x4 c){
  return __builtin_amdgcn_mfma_f32_16x16x32_bf16(a, b, c, 0, 0, 0);
}

__device__ __forceinline__ f32x2 pk_add(f32x2 a, f32x2 b){
  f32x2 d; asm("v_pk_add_f32 %0, %1, %2" : "=v"(d) : "v"(a), "v"(b)); return d;
}
__device__ __forceinline__ f32x2 pk_mul(f32x2 a, f32x2 b){
  f32x2 d; asm("v_pk_mul_f32 %0, %1, %2" : "=v"(d) : "v"(a), "v"(b)); return d;
}

#define DPP_FMAX(v, ctrl) do { \
  int _iv = __float_as_int(v); \
  int _sh = __builtin_amdgcn_update_dpp(_iv, _iv, (ctrl), 0xF, 0xF, false); \
  (v) = fmaxf((v), __int_as_float(_sh)); \
} while(0)

struct SMem {
  u64  masks[256];          // ballq chunk masks
  u64  wvkey[2][NW];        // fps per-wave keys (dbuf)
  float wvc[2][NW][4];      // fps per-wave winner coords (dbuf)
  float cxbuf[8][4];        // fps publish staging (t0)
  float xs[32][260];        // residual fp32 (padded stride)
  u16  xn[32][264];         // LN out / attn-out (bf16)
  u16  qb[32][776];         // qkv / FF hidden (bf16)
  u16  pb[NH][32][40];      // softmax P
  int  idx_sh[32];
  float gx_sh[32][3];
  int  misc[16];
  int  win[32];
};

// ---------------- prep ------------------------------------------------------
__global__ void k_prep(const float* __restrict__ ipw, const float* __restrict__ opw,
                       const float* __restrict__ fc1w, const float* __restrict__ fc2w,
                       const float* __restrict__ pe2w,
                       const float* __restrict__ bng, const float* __restrict__ bnb,
                       const float* __restrict__ bnm, const float* __restrict__ bnv,
                       u16* ipwb, u16* opwb, u16* fc1wb, u16* fc2wb, u16* pe2wb,
                       float* bnsc, float* bnsh, int* first, CtlBlock* ctl){
  const int i0 = blockIdx.x*blockDim.x + threadIdx.x;
  const int stride = gridDim.x*blockDim.x;
  for (int i=i0; i<NL*768*NC; i+=stride) ipwb[i] = f2bf(ipw[i]);
  for (int i=i0; i<NL*NC*NC; i+=stride)  opwb[i] = f2bf(opw[i]);
  for (int i=i0; i<NL*NDFF*NC; i+=stride) fc1wb[i] = f2bf(fc1w[i]);
  for (int i=i0; i<NL*NC*NDFF; i+=stride) fc2wb[i] = f2bf(fc2w[i]);
  for (int i=i0; i<NC*128; i+=stride)    pe2wb[i] = f2bf(pe2w[i]);
  for (int i=i0; i<NB*NN; i+=stride)     first[i] = LFv;
  for (int i=i0; i<128; i+=stride){
    float sc = bng[i]*rsqrtf(bnv[i]+LNEPS);
    bnsc[i] = sc; bnsh[i] = bnb[i] - bnm[i]*sc;
  }
  if (i0 == 0){
    ctl->prog[0] = -1; ctl->prog[1] = -1;
    ctl->ctr1 = 0; ctl->ctr2 = 0; ctl->bar = 0;
  }
}

// ---------------- featT -----------------------------------------------------
__global__ __launch_bounds__(256) void k_featT(const float* __restrict__ feat,
                                               float* __restrict__ featT){
  __shared__ float T[32][33];
  const int b = blockIdx.y;
  const int n0 = blockIdx.x*32;
  const int t = threadIdx.x;
  const int tn = t & 31, tc = t >> 5;
  for (int cb=0; cb<NC; cb+=32){
    #pragma unroll
    for (int i=0;i<32;i+=8)
      T[tc+i][tn] = feat[((size_t)b*NC + cb+tc+i)*NN + n0+tn];
    __syncthreads();
    #pragma unroll
    for (int i=0;i<32;i+=8)
      featT[((size_t)b*NN + n0+tc+i)*NC + cb+tn] = T[tn][tc+i];
    __syncthreads();
  }
}

#define SELC(S) case S: scx = px2[(S)>>1][(S)&1]; scy = py2[(S)>>1][(S)&1]; scz = pz2[(S)>>1][(S)&1]; break;

// ---------------- FPS role: fence-free, agent-atomic-published --------------
__device__ void fps_run(int b, const float* __restrict__ xyz, u64* __restrict__ cx2,
                        CtlBlock* ctl, SMem& sm){
#pragma clang fp contract(off)
  const int t = threadIdx.x;
  const int lane = t & 63, wid = t >> 6;
  const int wbase = wid*64;
  const float* xb = xyz + (size_t)b*NN*3;
  f32x2 px2[8], py2[8], pz2[8], dd2[8];
  #pragma unroll
  for (int m=0;m<8;m++){
    int i0 = t + (2*m)*NTHR, i1 = t + (2*m+1)*NTHR;
    px2[m] = f32x2{xb[i0*3],   xb[i1*3]};
    py2[m] = f32x2{xb[i0*3+1], xb[i1*3+1]};
    pz2[m] = f32x2{xb[i0*3+2], xb[i1*3+2]};
    dd2[m] = f32x2{1e10f, 1e10f};
  }
  float ncx, ncy, ncz;
  {
    float wx = xb[0], wy = xb[1], wz = xb[2];
    ncx=-wx; ncy=-wy; ncz=-wz;
    if (t==0){
      // FIX(r7): seed cxbuf[0] so the step-7 flush (s0=0, j=0) rewrites p=0
      // with the correct point-0 coords instead of uninitialized LDS.
      sm.cxbuf[0][0]=wx; sm.cxbuf[0][1]=wy; sm.cxbuf[0][2]=wz;
      u64 lo = ((u64)__float_as_uint(wy) << 32) | __float_as_uint(wx);
      u64 hi = (u64)__float_as_uint(wz);
      __hip_atomic_store(&cx2[(size_t)(b*NPp)*2],   lo, __ATOMIC_RELAXED, __HIP_MEMORY_SCOPE_AGENT);
      __hip_atomic_store(&cx2[(size_t)(b*NPp)*2+1], hi, __ATOMIC_RELAXED, __HIP_MEMORY_SCOPE_AGENT);
      asm volatile("s_waitcnt vmcnt(0)" ::: "memory");
      __hip_atomic_store(&ctl->prog[b], 0, __ATOMIC_RELAXED, __HIP_MEMORY_SCOPE_AGENT);
    }
  }
  __syncthreads();
  for (int step=1; step<NPp; ++step){
    const f32x2 ncx2={ncx,ncx}, ncy2={ncy,ncy}, ncz2={ncz,ncz};
    float bestv = -1.f;
    #pragma unroll
    for (int m=0;m<8;m++){
      f32x2 dx = pk_add(px2[m], ncx2);
      f32x2 dy = pk_add(py2[m], ncy2);
      f32x2 dz = pk_add(pz2[m], ncz2);
      f32x2 s  = pk_add(pk_add(pk_mul(dx,dx), pk_mul(dy,dy)), pk_mul(dz,dz));
      f32x2 d  = dd2[m];
      d.x = fminf(d.x, s.x);
      d.y = fminf(d.y, s.y);
      dd2[m] = d;
      bestv = fmaxf(fmaxf(bestv, d.x), d.y);   // v_max3-fusable
    }
    float M = bestv;
    DPP_FMAX(M, 0x111); DPP_FMAX(M, 0x112); DPP_FMAX(M, 0x114); DPP_FMAX(M, 0x118);
    DPP_FMAX(M, 0x142); DPP_FMAX(M, 0x143);
    const int Mi = __builtin_amdgcn_readlane(__float_as_int(M), 63);
    const float Ms = __int_as_float(Mi);
    // ballot per slot, SALU min-index pick (slot asc == idx asc)
    u64 bs[16];
    #pragma unroll
    for (int m=0;m<8;m++){
      bs[2*m]   = __ballot(dd2[m].x == Ms);
      bs[2*m+1] = __ballot(dd2[m].y == Ms);
    }
    int li = 0;
    #pragma unroll
    for (int s=15;s>=0;s--)
      if (bs[s]) li = wbase + s*NTHR + (__ffsll(bs[s])-1);
    const int sb = step & 1;
    if (lane==0)
      sm.wvkey[sb][wid] = ((u64)(unsigned)Mi << 32) | (unsigned)(0x7fffffff - li);
    {
      const int slot = li >> 10;                 // wave-uniform
      float scx=0.f, scy=0.f, scz=0.f;
      switch(slot){
        SELC(0) SELC(1) SELC(2) SELC(3) SELC(4) SELC(5) SELC(6) SELC(7)
        SELC(8) SELC(9) SELC(10) SELC(11) SELC(12) SELC(13) SELC(14) SELC(15)
        default: break;
      }
      if (t == (li & (NTHR-1))){                 // owner thread of this wave
        sm.wvc[sb][wid][0]=scx; sm.wvc[sb][wid][1]=scy; sm.wvc[sb][wid][2]=scz;
      }
    }
    __syncthreads();                             // the ONLY barrier per step
    // cross-wave merge: 16 keys via u64 shfl reduce (4 steps)
    u64 v = sm.wvkey[sb][lane & 15];
    #pragma unroll
    for (int m=1;m<16;m<<=1){
      u64 o = __shfl_xor(v, m);
      if (o > v) v = o;
    }
    const int widx = 0x7fffffff - (int)(unsigned)(v & 0xffffffffull);
    const int wv = (widx & (NTHR-1)) >> 6;
    const float bx = sm.wvc[sb][wv][0];
    const float by = sm.wvc[sb][wv][1];
    const float bz = sm.wvc[sb][wv][2];
    ncx=-bx; ncy=-by; ncz=-bz;
    if (t==0){
      sm.cxbuf[step & 7][0]=bx; sm.cxbuf[step & 7][1]=by; sm.cxbuf[step & 7][2]=bz;
      if ((step & 7) == 7){
        int s0 = step - 7;
        #pragma unroll
        for (int j=0;j<8;j++){
          float fx=sm.cxbuf[j][0], fy=sm.cxbuf[j][1], fz=sm.cxbuf[j][2];
          u64 lo = ((u64)__float_as_uint(fy) << 32) | __float_as_uint(fx);
          u64 hi = (u64)__float_as_uint(fz);
          size_t pb2 = (size_t)(b*NPp + s0 + j)*2;
          __hip_atomic_store(&cx2[pb2],   lo, __ATOMIC_RELAXED, __HIP_MEMORY_SCOPE_AGENT);
          __hip_atomic_store(&cx2[pb2+1], hi, __ATOMIC_RELAXED, __HIP_MEMORY_SCOPE_AGENT);
        }
      }
      if ((step & 7) == 0){
        // FIX(r7): make cx2->prog ordering architectural (drain own stores first)
        asm volatile("s_waitcnt vmcnt(0)" ::: "memory");
        __hip_atomic_store(&ctl->prog[b], step-1, __ATOMIC_RELAXED, __HIP_MEMORY_SCOPE_AGENT);
      }
    }
  }
  if (t==0){
    asm volatile("s_waitcnt vmcnt(0)" ::: "memory");
    __hip_atomic_store(&ctl->prog[b], NPp, __ATOMIC_RELAXED, __HIP_MEMORY_SCOPE_AGENT);
  }
}

// ---------------- inline ball query (1024 threads) --------------------------
__device__ void seq_ballq(const float* __restrict__ xb, float cx, float cy, float cz,
                          SMem& sm, int t, int lane, int wid){
#pragma clang fp contract(off)
  for (int it=0; it<16; ++it){
    int cid = wid*16 + it;
    int i = cid*64 + lane;
    float dx=xb[i*3]-cx, dy=xb[i*3+1]-cy, dz=xb[i*3+2]-cz;
    float d2=(dx*dx+dy*dy)+dz*dz;
    u64 m = __ballot(d2 < 1.0f);
    if (lane==0) sm.masks[cid] = m;
  }
  __syncthreads();
  if (wid==0){
    u64 mk[4]; int cnt=0;
    #pragma unroll
    for (int j=0;j<4;j++){ mk[j]=sm.masks[lane*4+j]; cnt += __popcll(mk[j]); }
    int inc = cnt;
    #pragma unroll
    for (int ofs=1; ofs<64; ofs<<=1){
      int v = __shfl_up(inc, ofs);
      if (lane >= ofs) inc += v;
    }
    int r = inc - cnt;
    int tot = __shfl(inc, 63);
    #pragma unroll
    for (int j=0;j<4;j++){
      u64 msk = mk[j];
      int base = (lane*4+j)*64;
      while (msk && r < NSs){
        int bpos = __ffsll(msk)-1;
        sm.idx_sh[r] = base + bpos;
        msk &= msk-1;
        ++r;
      }
      if (r >= NSs) break;
    }
    int cc = tot < NSs ? tot : NSs;
    int pv = (tot > 0) ? sm.idx_sh[0] : 0;
    if (lane < NSs && lane >= cc) sm.idx_sh[lane] = pv;
  }
  __syncthreads();
}

// ---------------- LN (1024 threads, 32 thr/row) -----------------------------
__device__ __forceinline__ void ln_block1024(SMem& sm, const float* __restrict__ s_,
                                             const float* __restrict__ b_, int t){
  const int s = t >> 5, j = t & 31;
  float v[8];
  float sum = 0.f;
  #pragma unroll
  for (int k=0;k<8;k++){ v[k]=sm.xs[s][j*8+k]; sum += v[k]; }
  #pragma unroll
  for (int m=1;m<32;m<<=1) sum += __shfl_xor(sum, m);
  const float mean = sum * (1.f/256.f);
  float vs = 0.f;
  #pragma unroll
  for (int k=0;k<8;k++){ float d=v[k]-mean; vs += d*d; }
  #pragma unroll
  for (int m=1;m<32;m<<=1) vs += __shfl_xor(vs, m);
  const float rstd = rsqrtf(vs*(1.f/256.f) + LNEPS);
  #pragma unroll
  for (int k=0;k<8;k++){
    int c = j*8+k;
    float y = (v[k]-mean)*rstd*s_[c] + b_[c];
    sm.xs[s][c] = y;
    sm.xn[s][c] = f2bf(y);
  }
}

// ---------------- PE + transformer (1024 threads, 16 waves) -----------------
__device__ void seq_pe_tf(SMem& sm, int b, float ccx, float ccy, float ccz,
    const float* __restrict__ xyz, const float* __restrict__ features,
    const float* __restrict__ featT, int useT,
    const float* __restrict__ pe1w, const float* __restrict__ pe1b,
    const float* __restrict__ bnsc, const float* __restrict__ bnsh,
    const u16* __restrict__ pe2wb, const float* __restrict__ pe2b,
    const u16* __restrict__ ipwb, const float* __restrict__ ipb,
    const u16* __restrict__ opwb, const float* __restrict__ opb,
    const float* __restrict__ ln1s, const float* __restrict__ ln1b,
    const float* __restrict__ ln2s, const float* __restrict__ ln2b,
    const u16* __restrict__ fc1wb, const float* __restrict__ fc1b,
    const u16* __restrict__ fc2wb, const float* __restrict__ fc2b){
  const int t = threadIdx.x, lane = t & 63, wid = t >> 6;
  const int c15 = lane & 15, g4 = lane >> 4;

  if (t < 96){
    int s = t/3, d = t%3;
    float cd = (d==0) ? ccx : ((d==1) ? ccy : ccz);
    sm.gx_sh[s][d] = xyz[((size_t)b*NN + sm.idx_sh[s])*3 + d] - cd;
  }
  if (useT){
    for (int e=t; e<32*NC; e+=NTHR){
      int s=e>>8, c=e&255;
      sm.xs[s][c] = featT[((size_t)b*NN + sm.idx_sh[s])*NC + c];
    }
  } else {
    for (int e=t; e<32*NC; e+=NTHR){
      int s=e>>8, c=e&255;
      sm.xs[s][c] = features[((size_t)b*NC + c)*NN + sm.idx_sh[s]];
    }
  }
  __syncthreads();
  for (int i=t; i<32*128; i+=NTHR){
    int s = i >> 7, o = i & 127;
    float h = pe1w[o*3]*sm.gx_sh[s][0] + pe1w[o*3+1]*sm.gx_sh[s][1] + pe1w[o*3+2]*sm.gx_sh[s][2] + pe1b[o];
    h = h*bnsc[o] + bnsh[o];
    sm.xn[s][o] = f2bf(h > 0.f ? h : 0.f);
  }
  __syncthreads();
  for (int tt=wid; tt<32; tt+=NW){
    int m0 = (tt & 1)*16, n0 = (tt >> 1)*16;
    f32x4 acc = {0.f,0.f,0.f,0.f};
    #pragma unroll
    for (int kk=0; kk<4; kk++){
      s16x8 a = *(const s16x8*)&sm.xn[m0+c15][kk*32 + g4*8];
      s16x8 bb = *(const s16x8*)&pe2wb[(size_t)(n0+c15)*128 + kk*32 + g4*8];
      acc = mfma16(a, bb, acc);
    }
    int col = n0 + c15;
    float bias = pe2b[col];
    #pragma unroll
    for (int r=0;r<4;r++) sm.xs[m0 + g4*4 + r][col] += acc[r] + bias;
  }
  __syncthreads();

  for (int l=0; l<NL; ++l){
    ln_block1024(sm, ln1s + l*NC, ln1b + l*NC, t);
    __syncthreads();
    const u16* Wq = ipwb + (size_t)l*768*NC;
    const float* bq = ipb + l*768;
    for (int tt=wid; tt<96; tt+=NW){
      int m0 = (tt & 1)*16, n0 = (tt >> 1)*16;
      f32x4 acc = {0.f,0.f,0.f,0.f};
      #pragma unroll
      for (int kk=0;kk<8;kk++){
        s16x8 a = *(const s16x8*)&sm.xn[m0+c15][kk*32 + g4*8];
        s16x8 bb = *(const s16x8*)&Wq[(size_t)(n0+c15)*NC + kk*32 + g4*8];
        acc = mfma16(a, bb, acc);
      }
      int col = n0 + c15;
      float bias = bq[col];
      #pragma unroll
      for (int r=0;r<4;r++) sm.qb[m0 + g4*4 + r][col] = f2bf(acc[r] + bias);
    }
    __syncthreads();
    {
      const int h = wid & 3;
      const int mt = (wid >> 2) & 1;
      f32x4 oac[4];
      if (wid < 8){
        f32x4 lac[2];
        #pragma unroll
        for (int nt=0;nt<2;nt++){
          f32x4 acc = {0.f,0.f,0.f,0.f};
          #pragma unroll
          for (int kk=0;kk<2;kk++){
            s16x8 a = *(const s16x8*)&sm.qb[mt*16+c15][h*HDh + kk*32 + g4*8];
            s16x8 bb = *(const s16x8*)&sm.qb[nt*16+c15][256 + h*HDh + kk*32 + g4*8];
            acc = mfma16(a, bb, acc);
          }
          lac[nt] = acc;
        }
        #pragma unroll
        for (int r=0;r<4;r++){
          float v0 = lac[0][r]*0.125f, v1 = lac[1][r]*0.125f;
          float mx = fmaxf(v0, v1);
          #pragma unroll
          for (int m=1;m<16;m<<=1) mx = fmaxf(mx, __shfl_xor(mx, m));
          float e0 = expf(v0-mx), e1 = expf(v1-mx);
          float smm = e0 + e1;
          #pragma unroll
          for (int m=1;m<16;m<<=1) smm += __shfl_xor(smm, m);
          float inv = 1.f/smm;
          int row = mt*16 + g4*4 + r;
          sm.pb[h][row][c15]    = f2bf(e0*inv);
          sm.pb[h][row][16+c15] = f2bf(e1*inv);
        }
        #pragma unroll
        for (int nt=0;nt<4;nt++){
          s16x8 bb;
          #pragma unroll
          for (int e=0;e<8;e++) bb[e] = (short)sm.qb[g4*8+e][512 + h*HDh + nt*16 + c15];
          f32x4 acc = {0.f,0.f,0.f,0.f};
          s16x8 a = *(const s16x8*)&sm.pb[h][mt*16+c15][g4*8];
          oac[nt] = mfma16(a, bb, acc);
        }
      }
      __syncthreads();   // qkv consumed; xn free
      if (wid < 8){
        #pragma unroll
        for (int nt=0;nt<4;nt++)
          #pragma unroll
          for (int r=0;r<4;r++)
            sm.xn[mt*16 + g4*4 + r][h*HDh + nt*16 + c15] = f2bf(oac[nt][r]);
      }
    }
    __syncthreads();
    const u16* Wo = opwb + (size_t)l*NC*NC;
    const float* bo = opb + l*NC;
    for (int tt=wid; tt<32; tt+=NW){
      int m0 = (tt & 1)*16, n0 = (tt >> 1)*16;
      f32x4 acc = {0.f,0.f,0.f,0.f};
      #pragma unroll
      for (int kk=0;kk<8;kk++){
        s16x8 a = *(const s16x8*)&sm.xn[m0+c15][kk*32 + g4*8];
        s16x8 bb = *(const s16x8*)&Wo[(size_t)(n0+c15)*NC + kk*32 + g4*8];
        acc = mfma16(a, bb, acc);
      }
      int col = n0 + c15;
      float bias = bo[col];
      #pragma unroll
      for (int r=0;r<4;r++) sm.xs[m0 + g4*4 + r][col] += acc[r] + bias;
    }
    __syncthreads();
    ln_block1024(sm, ln2s + l*NC, ln2b + l*NC, t);
    __syncthreads();
    const u16* W1 = fc1wb + (size_t)l*NDFF*NC;
    for (int tt=wid; tt<64; tt+=NW){
      int m0 = (tt & 1)*16, n0 = (tt >> 1)*16;
      f32x4 acc = {0.f,0.f,0.f,0.f};
      #pragma unroll
      for (int kk=0;kk<8;kk++){
        s16x8 a = *(const s16x8*)&sm.xn[m0+c15][kk*32 + g4*8];
        s16x8 bb = *(const s16x8*)&W1[(size_t)(n0+c15)*NC + kk*32 + g4*8];
        acc = mfma16(a, bb, acc);
      }
      int col = n0 + c15;
      float bias = fc1b[l*NDFF + col];
      #pragma unroll
      for (int r=0;r<4;r++){
        float v = acc[r] + bias;
        sm.qb[m0 + g4*4 + r][col] = f2bf(v > 0.f ? v : 0.f);
      }
    }
    __syncthreads();
    const u16* W2 = fc2wb + (size_t)l*NC*NDFF;
    for (int tt=wid; tt<32; tt+=NW){
      int m0 = (tt & 1)*16, n0 = (tt >> 1)*16;
      f32x4 acc = {0.f,0.f,0.f,0.f};
      #pragma unroll
      for (int kk=0;kk<16;kk++){
        s16x8 a = *(const s16x8*)&sm.qb[m0+c15][kk*32 + g4*8];
        s16x8 bb = *(const s16x8*)&W2[(size_t)(n0+c15)*NDFF + kk*32 + g4*8];
        acc = mfma16(a, bb, acc);
      }
      int col = n0 + c15;
      float bias = fc2b[l*NC + col];
      #pragma unroll
      for (int r=0;r<4;r++) sm.xs[m0 + g4*4 + r][col] += acc[r] + bias;
    }
    __syncthreads();
  }
}

// ---------------- mega kernel ----------------------------------------------
__global__ __launch_bounds__(NTHR) void k_mega(
    const float* __restrict__ xyz, const float* __restrict__ features,
    const float* __restrict__ featT, int useT, u16* __restrict__ tfb, int spec,
    u64* __restrict__ cx2, int* __restrict__ first, CtlBlock* ctl,
    const float* __restrict__ pe1w, const float* __restrict__ pe1b,
    const float* __restrict__ bnsc, const float* __restrict__ bnsh,
    const u16* __restrict__ pe2wb, const float* __restrict__ pe2b,
    const u16* __restrict__ ipwb, const float* __restrict__ ipb,
    const u16* __restrict__ opwb, const float* __restrict__ opb,
    const float* __restrict__ ln1s, const float* __restrict__ ln1b,
    const float* __restrict__ ln2s, const float* __restrict__ ln2b,
    const u16* __restrict__ fc1wb, const float* __restrict__ fc1b,
    const u16* __restrict__ fc2wb, const float* __restrict__ fc2b,
    float* __restrict__ out){
  __shared__ SMem sm;
  const int t = threadIdx.x, lane = t & 63, wid = t >> 6;

  if (blockIdx.x < NB){
    fps_run(blockIdx.x, xyz, cx2, ctl, sm);
  } else {
    for (;;){
      if (t==0) sm.misc[1] = atomicAdd(&ctl->ctr1, 1);
      __syncthreads();
      int p = sm.misc[1];
      if (p >= NB*NPp) break;
      int b = p >> 11, pp = p & (NPp-1);
      if (t==0){
        while (__hip_atomic_load(&ctl->prog[b], __ATOMIC_RELAXED, __HIP_MEMORY_SCOPE_AGENT) < pp)
          __builtin_amdgcn_s_sleep(2);
        asm volatile("" ::: "memory");
        u64 lo = __hip_atomic_load(&cx2[(size_t)p*2],   __ATOMIC_RELAXED, __HIP_MEMORY_SCOPE_AGENT);
        u64 hi = __hip_atomic_load(&cx2[(size_t)p*2+1], __ATOMIC_RELAXED, __HIP_MEMORY_SCOPE_AGENT);
        sm.misc[4] = (int)(unsigned)(lo & 0xffffffffull);
        sm.misc[5] = (int)(unsigned)(lo >> 32);
        sm.misc[6] = (int)(unsigned)(hi & 0xffffffffull);
      }
      __syncthreads();
      float cx = __int_as_float(sm.misc[4]);
      float cy = __int_as_float(sm.misc[5]);
      float cz = __int_as_float(sm.misc[6]);
      seq_ballq(xyz + (size_t)b*NN*3, cx, cy, cz, sm, t, lane, wid);
      if (t < NSs) atomicMin(&first[b*NN + sm.idx_sh[t]], pp*NSs + t);
      if (spec){
        seq_pe_tf(sm, b, cx, cy, cz, xyz, features, featT, useT,
                  pe1w, pe1b, bnsc, bnsh, pe2wb, pe2b, ipwb, ipb, opwb, opb,
                  ln1s, ln1b, ln2s, ln2b, fc1wb, fc1b, fc2wb, fc2b);
        for (int e=t; e<NSs*NC; e+=NTHR)
          tfb[(size_t)p*NSs*NC + e] = f2bf(sm.xs[e>>8][e&255]);
      }
      __syncthreads();
    }
  }
  if (spec) return;

  // -------- fallback path: fenced grid barrier + phase 2 --------------------
  __syncthreads();
  if (t==0){
    __builtin_amdgcn_fence(__ATOMIC_RELEASE, "agent");
    __hip_atomic_fetch_add(&ctl->bar, 1, __ATOMIC_RELAXED, __HIP_MEMORY_SCOPE_AGENT);
    while (__hip_atomic_load(&ctl->bar, __ATOMIC_RELAXED, __HIP_MEMORY_SCOPE_AGENT) < NBLK)
      __builtin_amdgcn_s_sleep(8);
    __builtin_amdgcn_fence(__ATOMIC_ACQUIRE, "agent");
  }
  __syncthreads();
  for (;;){
    if (t==0) sm.misc[1] = atomicAdd(&ctl->ctr2, 1);
    __syncthreads();
    int p = sm.misc[1];
    if (p >= NB*NPp) break;
    int b = p >> 11, pp = p & (NPp-1);
    u64 lo = cx2[(size_t)p*2], hi = cx2[(size_t)p*2+1];
    float cx = __int_as_float((int)(unsigned)(lo & 0xffffffffull));
    float cy = __int_as_float((int)(unsigned)(lo >> 32));
    float cz = __int_as_float((int)(unsigned)(hi & 0xffffffffull));
    seq_ballq(xyz + (size_t)b*NN*3, cx, cy, cz, sm, t, lane, wid);
    if (t==0) sm.misc[2] = 0;
    __syncthreads();
    if (t < NSs){
      int pos = pp*NSs + t;
      int f = __hip_atomic_load(&first[b*NN + sm.idx_sh[t]], __ATOMIC_RELAXED, __HIP_MEMORY_SCOPE_AGENT);
      int w = (f == pos) ? 1 : 0;
      sm.win[t] = w;
      if (w) atomicOr(&sm.misc[2], 1);
    }
    __syncthreads();
    if (!sm.misc[2]) continue;
    seq_pe_tf(sm, b, cx, cy, cz, xyz, features, featT, useT,
              pe1w, pe1b, bnsc, bnsh, pe2wb, pe2b, ipwb, ipb, opwb, opb,
              ln1s, ln1b, ln2s, ln2b, fc1wb, fc1b, fc2wb, fc2b);
    for (int e=t; e<NSs*NC; e+=NTHR){
      int s = e >> 8, c = e & 255;
      if (sm.win[s]) out[((size_t)b*NN + sm.idx_sh[s])*NC + c] = sm.xs[s][c];
    }
    __syncthreads();
  }
}

// ---------------- commit ----------------------------------------------------
__global__ __launch_bounds__(256) void k_commit(const u16* __restrict__ tfb,
                                                const int* __restrict__ first,
                                                const float* __restrict__ featT,
                                                const float* __restrict__ feat,
                                                int useT, float* __restrict__ out){
  const int t = threadIdx.x;
  const int row0 = blockIdx.x*16;
  for (int r=0;r<16;++r){
    int row = row0 + r;
    int b = row >> 14;
    int f = first[row];
    float v;
    if (f != LFv){
      unsigned u = tfb[((size_t)b*NPp*NSs + f)*NC + t];
      v = __int_as_float((int)(u << 16));
    } else if (useT){
      v = featT[(size_t)row*NC + t];
    } else {
      int n = row & (NN-1);
      v = feat[((size_t)b*NC + t)*NN + n];
    }
    out[(size_t)row*NC + t] = v;
  }
}

// ---------------- fallback fill --------------------------------------------
__global__ __launch_bounds__(256) void k_outfill_T(const float* __restrict__ featT,
                                                   const int* __restrict__ first,
                                                   float* __restrict__ out){
  const int t = threadIdx.x;
  for (int rr=0; rr<8; ++rr){
    int row = blockIdx.x*8 + rr;
    if (first[row] == LFv)
      out[(size_t)row*NC + t] = featT[(size_t)row*NC + t];
  }
}

__global__ __launch_bounds__(256) void k_outfill_noT(const float* __restrict__ feat,
                                                     const int* __restrict__ first,
                                                     float* __restrict__ out){
  __shared__ float T[32][33];
  const int b = blockIdx.y;
  const int n0 = blockIdx.x*32;
  const int t = threadIdx.x;
  const int tn = t & 31, tc = t >> 5;
  for (int cb=0; cb<NC; cb+=32){
    #pragma unroll
    for (int i=0;i<32;i+=8)
      T[tc+i][tn] = feat[((size_t)b*NC + cb+tc+i)*NN + n0+tn];
    __syncthreads();
    #pragma unroll
    for (int i=0;i<32;i+=8){
      int n = n0 + tc + i;
      if (first[b*NN+n] == LFv)
        out[((size_t)b*NN + n)*NC + cb+tn] = T[tn][tc+i];
    }
    __syncthreads();
  }
}

extern "C" void kernel_launch(void* const* d_in, const int* in_sizes, int n_in,
                              void* d_out, int out_size, void* d_ws, size_t ws_size,
                              hipStream_t stream){
  const float* xyz   = (const float*)d_in[0];
  const float* feat  = (const float*)d_in[1];
  const float* pe1w  = (const float*)d_in[2];
  const float* pe1b  = (const float*)d_in[3];
  const float* bng   = (const float*)d_in[4];
  const float* bnb   = (const float*)d_in[5];
  const float* bnm   = (const float*)d_in[6];
  const float* bnv   = (const float*)d_in[7];
  const float* pe2w  = (const float*)d_in[8];
  const float* pe2b  = (const float*)d_in[9];
  const float* ipw   = (const float*)d_in[10];
  const float* ipb   = (const float*)d_in[11];
  const float* opw   = (const float*)d_in[12];
  const float* opb   = (const float*)d_in[13];
  const float* ln1s  = (const float*)d_in[14];
  const float* ln1b  = (const float*)d_in[15];
  const float* ln2s  = (const float*)d_in[16];
  const float* ln2b  = (const float*)d_in[17];
  const float* fc1w  = (const float*)d_in[18];
  const float* fc1b  = (const float*)d_in[19];
  const float* fc2w  = (const float*)d_in[20];
  const float* fc2b  = (const float*)d_in[21];
  float* out = (float*)d_out;

  char* ws = (char*)d_ws;
  size_t off = 0;
  auto alloc = [&](size_t bytes)->void*{
    void* p = ws + off;
    off = (off + bytes + 255) & ~(size_t)255;
    return p;
  };
  u64*   cx2     = (u64*)  alloc((size_t)NB*NPp*2*8);
  int*   first   = (int*)  alloc((size_t)NB*NN*4);
  CtlBlock* ctl  = (CtlBlock*)alloc(sizeof(CtlBlock));
  float* bnsc    = (float*)alloc(128*4);
  float* bnsh    = (float*)alloc(128*4);
  u16*   ipwb    = (u16*)  alloc((size_t)NL*768*NC*2);
  u16*   opwb    = (u16*)  alloc((size_t)NL*NC*NC*2);
  u16*   fc1wb   = (u16*)  alloc((size_t)NL*NDFF*NC*2);
  u16*   fc2wb   = (u16*)  alloc((size_t)NL*NC*NDFF*2);
  u16*   pe2wb   = (u16*)  alloc((size_t)NC*128*2);
  int useT = (off + (size_t)NB*NN*NC*4 <= ws_size) ? 1 : 0;
  float* featT = (float*)(useT ? alloc((size_t)NB*NN*NC*4) : (void*)ws);
  int spec = (off + (size_t)NB*NPp*NSs*NC*2 <= ws_size) ? 1 : 0;
  u16* tfb = (u16*)(spec ? alloc((size_t)NB*NPp*NSs*NC*2) : (void*)ws);

  k_prep<<<512, 256, 0, stream>>>(ipw, opw, fc1w, fc2w, pe2w, bng, bnb, bnm, bnv,
                                  ipwb, opwb, fc1wb, fc2wb, pe2wb, bnsc, bnsh, first, ctl);
  if (useT)
    k_featT<<<dim3(NN/32, NB), 256, 0, stream>>>(feat, featT);

  const float* featT_c = featT;
  void* kargs[] = {
    (void*)&xyz, (void*)&feat, (void*)&featT_c, (void*)&useT, (void*)&tfb, (void*)&spec,
    (void*)&cx2, (void*)&first, (void*)&ctl,
    (void*)&pe1w, (void*)&pe1b, (void*)&bnsc, (void*)&bnsh,
    (void*)&pe2wb, (void*)&pe2b, (void*)&ipwb, (void*)&ipb,
    (void*)&opwb, (void*)&opb, (void*)&ln1s, (void*)&ln1b,
    (void*)&ln2s, (void*)&ln2b, (void*)&fc1wb, (void*)&fc1b,
    (void*)&fc2wb, (void*)&fc2b, (void*)&out };
  hipLaunchCooperativeKernel((void*)k_mega, dim3(NBLK), dim3(NTHR), kargs, 0, stream);

  if (spec){
    k_commit<<<(NB*NN)/16, 256, 0, stream>>>(tfb, first, featT, feat, useT, out);
  } else if (useT){
    k_outfill_T<<<(NB*NN)/8, 256, 0, stream>>>(featT, first, out);
  } else {
    k_outfill_noT<<<dim3(NN/32, NB), 256, 0, stream>>>(feat, first, out);
  }
  (void)in_sizes; (void)n_in; (void)out_size;
}

// Round 9
// 5712.384 us; speedup vs baseline: 1.0042x; 1.0042x over previous
//
#include <hip/hip_runtime.h>

#define NB 2
#define NN 16384
#define NC 256
#define NPp 2048
#define NSs 32
#define NH 4
#define HDh 64
#define NL 2
#define NDFF 512
#define LFv (NPp*NSs)
#define LNEPS 1e-5f
#define NBLK 256
#define NTHR 1024
#define NW 16

typedef short s16x8 __attribute__((ext_vector_type(8)));
typedef float f32x4 __attribute__((ext_vector_type(4)));
typedef float f32x2 __attribute__((ext_vector_type(2)));
typedef unsigned short u16;
typedef unsigned long long u64;

struct CtlBlock { int prog[2]; int ctr1; int ctr2; int bar; };

__device__ __forceinline__ u16 f2bf(float f){
  unsigned u = __float_as_uint(f);
  u += 0x7fffu + ((u>>16)&1u);
  return (u16)(u>>16);
}

__device__ __forceinline__ f32x4 mfma16(s16x8 a, s16x8 b, f32x4 c){
  return __builtin_amdgcn_mfma_f32_16x16x32_bf16(a, b, c, 0, 0, 0);
}

__device__ __forceinline__ f32x2 pk_add(f32x2 a, f32x2 b){
  f32x2 d; asm("v_pk_add_f32 %0, %1, %2" : "=v"(d) : "v"(a), "v"(b)); return d;
}
__device__ __forceinline__ f32x2 pk_mul(f32x2 a, f32x2 b){
  f32x2 d; asm("v_pk_mul_f32 %0, %1, %2" : "=v"(d) : "v"(a), "v"(b)); return d;
}

#define DPP_FMAX(v, ctrl) do { \
  int _iv = __float_as_int(v); \
  int _sh = __builtin_amdgcn_update_dpp(_iv, _iv, (ctrl), 0xF, 0xF, false); \
  (v) = fmaxf((v), __int_as_float(_sh)); \
} while(0)

struct SMem {
  u64  masks[256];
  u64  wvkey[2][NW];
  float wvc[2][NW][4];
  float cxbuf[8][4];
  float xs[32][260];
  u16  xn[32][264];
  u16  qb[32][776];
  u16  pb[NH][32][40];
  int  idx_sh[32];
  float gx_sh[32][3];
  int  misc[16];
  int  win[32];
};

// ---------------- prep ------------------------------------------------------
__global__ void k_prep(const float* __restrict__ ipw, const float* __restrict__ opw,
                       const float* __restrict__ fc1w, const float* __restrict__ fc2w,
                       const float* __restrict__ pe2w,
                       const float* __restrict__ bng, const float* __restrict__ bnb,
                       const float* __restrict__ bnm, const float* __restrict__ bnv,
                       u16* ipwb, u16* opwb, u16* fc1wb, u16* fc2wb, u16* pe2wb,
                       float* bnsc, float* bnsh, int* first, CtlBlock* ctl){
  const int i0 = blockIdx.x*blockDim.x + threadIdx.x;
  const int stride = gridDim.x*blockDim.x;
  for (int i=i0; i<NL*768*NC; i+=stride) ipwb[i] = f2bf(ipw[i]);
  for (int i=i0; i<NL*NC*NC; i+=stride)  opwb[i] = f2bf(opw[i]);
  for (int i=i0; i<NL*NDFF*NC; i+=stride) fc1wb[i] = f2bf(fc1w[i]);
  for (int i=i0; i<NL*NC*NDFF; i+=stride) fc2wb[i] = f2bf(fc2w[i]);
  for (int i=i0; i<NC*128; i+=stride)    pe2wb[i] = f2bf(pe2w[i]);
  for (int i=i0; i<NB*NN; i+=stride)     first[i] = LFv;
  for (int i=i0; i<128; i+=stride){
    float sc = bng[i]*rsqrtf(bnv[i]+LNEPS);
    bnsc[i] = sc; bnsh[i] = bnb[i] - bnm[i]*sc;
  }
  if (i0 == 0){
    ctl->prog[0] = -1; ctl->prog[1] = -1;
    ctl->ctr1 = 0; ctl->ctr2 = 0; ctl->bar = 0;
  }
}

// ---------------- featT -----------------------------------------------------
__global__ __launch_bounds__(256) void k_featT(const float* __restrict__ feat,
                                               float* __restrict__ featT){
  __shared__ float T[32][33];
  const int b = blockIdx.y;
  const int n0 = blockIdx.x*32;
  const int t = threadIdx.x;
  const int tn = t & 31, tc = t >> 5;
  for (int cb=0; cb<NC; cb+=32){
    #pragma unroll
    for (int i=0;i<32;i+=8)
      T[tc+i][tn] = feat[((size_t)b*NC + cb+tc+i)*NN + n0+tn];
    __syncthreads();
    #pragma unroll
    for (int i=0;i<32;i+=8)
      featT[((size_t)b*NN + n0+tc+i)*NC + cb+tn] = T[tn][tc+i];
    __syncthreads();
  }
}

// ---- FPS hot state as NAMED f32x2 variables (no arrays -> no scratch) -----
#define FPS_DECL(M) f32x2 px##M, py##M, pz##M, dd##M;
#define FPS_INIT(M) { int i0_ = t + (2*(M))*NTHR, i1_ = t + (2*(M)+1)*NTHR; \
  px##M = f32x2{xb[i0_*3],   xb[i1_*3]}; \
  py##M = f32x2{xb[i0_*3+1], xb[i1_*3+1]}; \
  pz##M = f32x2{xb[i0_*3+2], xb[i1_*3+2]}; \
  dd##M = f32x2{1e10f, 1e10f}; }
#define FPS_STEP(M) { \
  f32x2 dx_ = pk_add(px##M, ncx2); \
  f32x2 dy_ = pk_add(py##M, ncy2); \
  f32x2 dz_ = pk_add(pz##M, ncz2); \
  f32x2 s_  = pk_add(pk_add(pk_mul(dx_,dx_), pk_mul(dy_,dy_)), pk_mul(dz_,dz_)); \
  dd##M.x = fminf(dd##M.x, s_.x); \
  dd##M.y = fminf(dd##M.y, s_.y); \
  bestv = fmaxf(fmaxf(bestv, dd##M.x), dd##M.y); }
#define FPS_BAL(M) \
  bs[2*(M)]   = __ballot(dd##M.x == Ms); \
  bs[2*(M)+1] = __ballot(dd##M.y == Ms);
#define FPS_SEL(M) \
  case 2*(M):   scx = px##M.x; scy = py##M.x; scz = pz##M.x; break; \
  case 2*(M)+1: scx = px##M.y; scy = py##M.y; scz = pz##M.y; break;

// ---------------- FPS role: fence-free, agent-atomic-published --------------
__device__ void fps_run(int b, const float* __restrict__ xyz, u64* __restrict__ cx2,
                        CtlBlock* ctl, SMem& sm){
#pragma clang fp contract(off)
  const int t = threadIdx.x;
  const int lane = t & 63, wid = t >> 6;
  const int wbase = wid*64;
  const float* xb = xyz + (size_t)b*NN*3;
  FPS_DECL(0) FPS_DECL(1) FPS_DECL(2) FPS_DECL(3)
  FPS_DECL(4) FPS_DECL(5) FPS_DECL(6) FPS_DECL(7)
  FPS_INIT(0) FPS_INIT(1) FPS_INIT(2) FPS_INIT(3)
  FPS_INIT(4) FPS_INIT(5) FPS_INIT(6) FPS_INIT(7)
  float ncx, ncy, ncz;
  {
    float wx = xb[0], wy = xb[1], wz = xb[2];
    ncx=-wx; ncy=-wy; ncz=-wz;
    if (t==0){
      sm.cxbuf[0][0]=wx; sm.cxbuf[0][1]=wy; sm.cxbuf[0][2]=wz;
      u64 lo = ((u64)__float_as_uint(wy) << 32) | __float_as_uint(wx);
      u64 hi = (u64)__float_as_uint(wz);
      __hip_atomic_store(&cx2[(size_t)(b*NPp)*2],   lo, __ATOMIC_RELAXED, __HIP_MEMORY_SCOPE_AGENT);
      __hip_atomic_store(&cx2[(size_t)(b*NPp)*2+1], hi, __ATOMIC_RELAXED, __HIP_MEMORY_SCOPE_AGENT);
      asm volatile("s_waitcnt vmcnt(0)" ::: "memory");
      __hip_atomic_store(&ctl->prog[b], 0, __ATOMIC_RELAXED, __HIP_MEMORY_SCOPE_AGENT);
    }
  }
  __syncthreads();
  for (int step=1; step<NPp; ++step){
    const f32x2 ncx2={ncx,ncx}, ncy2={ncy,ncy}, ncz2={ncz,ncz};
    float bestv = -1.f;
    FPS_STEP(0) FPS_STEP(1) FPS_STEP(2) FPS_STEP(3)
    FPS_STEP(4) FPS_STEP(5) FPS_STEP(6) FPS_STEP(7)
    float M = bestv;
    DPP_FMAX(M, 0x111); DPP_FMAX(M, 0x112); DPP_FMAX(M, 0x114); DPP_FMAX(M, 0x118);
    DPP_FMAX(M, 0x142); DPP_FMAX(M, 0x143);
    const int Mi = __builtin_amdgcn_readlane(__float_as_int(M), 63);
    const float Ms = __int_as_float(Mi);
    u64 bs[16];
    FPS_BAL(0) FPS_BAL(1) FPS_BAL(2) FPS_BAL(3)
    FPS_BAL(4) FPS_BAL(5) FPS_BAL(6) FPS_BAL(7)
    int li = 0;
    #pragma unroll
    for (int s=15;s>=0;s--)
      if (bs[s]) li = wbase + s*NTHR + (__ffsll(bs[s])-1);
    const int sb = step & 1;
    if (lane==0)
      sm.wvkey[sb][wid] = ((u64)(unsigned)Mi << 32) | (unsigned)(0x7fffffff - li);
    {
      const int slot = li >> 10;                 // wave-uniform
      float scx=0.f, scy=0.f, scz=0.f;
      switch(slot){
        FPS_SEL(0) FPS_SEL(1) FPS_SEL(2) FPS_SEL(3)
        FPS_SEL(4) FPS_SEL(5) FPS_SEL(6) FPS_SEL(7)
        default: break;
      }
      if (t == (li & (NTHR-1))){                 // owner thread of this wave
        sm.wvc[sb][wid][0]=scx; sm.wvc[sb][wid][1]=scy; sm.wvc[sb][wid][2]=scz;
      }
    }
    __syncthreads();                             // the ONLY barrier per step
    u64 v = sm.wvkey[sb][lane & 15];
    #pragma unroll
    for (int m=1;m<16;m<<=1){
      u64 o = __shfl_xor(v, m);
      if (o > v) v = o;
    }
    const int widx = 0x7fffffff - (int)(unsigned)(v & 0xffffffffull);
    const int wv = (widx & (NTHR-1)) >> 6;
    const float bx = sm.wvc[sb][wv][0];
    const float by = sm.wvc[sb][wv][1];
    const float bz = sm.wvc[sb][wv][2];
    ncx=-bx; ncy=-by; ncz=-bz;
    if (t==0){
      sm.cxbuf[step & 7][0]=bx; sm.cxbuf[step & 7][1]=by; sm.cxbuf[step & 7][2]=bz;
      if ((step & 7) == 7){
        int s0 = step - 7;
        #pragma unroll
        for (int j=0;j<8;j++){
          float fx=sm.cxbuf[j][0], fy=sm.cxbuf[j][1], fz=sm.cxbuf[j][2];
          u64 lo = ((u64)__float_as_uint(fy) << 32) | __float_as_uint(fx);
          u64 hi = (u64)__float_as_uint(fz);
          size_t pb2 = (size_t)(b*NPp + s0 + j)*2;
          __hip_atomic_store(&cx2[pb2],   lo, __ATOMIC_RELAXED, __HIP_MEMORY_SCOPE_AGENT);
          __hip_atomic_store(&cx2[pb2+1], hi, __ATOMIC_RELAXED, __HIP_MEMORY_SCOPE_AGENT);
        }
      }
      if ((step & 7) == 0){
        asm volatile("s_waitcnt vmcnt(0)" ::: "memory");
        __hip_atomic_store(&ctl->prog[b], step-1, __ATOMIC_RELAXED, __HIP_MEMORY_SCOPE_AGENT);
      }
    }
  }
  if (t==0){
    asm volatile("s_waitcnt vmcnt(0)" ::: "memory");
    __hip_atomic_store(&ctl->prog[b], NPp, __ATOMIC_RELAXED, __HIP_MEMORY_SCOPE_AGENT);
  }
}

// ---------------- inline ball query (1024 threads) --------------------------
__device__ void seq_ballq(const float* __restrict__ xb, float cx, float cy, float cz,
                          SMem& sm, int t, int lane, int wid){
#pragma clang fp contract(off)
  for (int it=0; it<16; ++it){
    int cid = wid*16 + it;
    int i = cid*64 + lane;
    float dx=xb[i*3]-cx, dy=xb[i*3+1]-cy, dz=xb[i*3+2]-cz;
    float d2=(dx*dx+dy*dy)+dz*dz;
    u64 m = __ballot(d2 < 1.0f);
    if (lane==0) sm.masks[cid] = m;
  }
  __syncthreads();
  if (wid==0){
    u64 mk[4]; int cnt=0;
    #pragma unroll
    for (int j=0;j<4;j++){ mk[j]=sm.masks[lane*4+j]; cnt += __popcll(mk[j]); }
    int inc = cnt;
    #pragma unroll
    for (int ofs=1; ofs<64; ofs<<=1){
      int v = __shfl_up(inc, ofs);
      if (lane >= ofs) inc += v;
    }
    int r = inc - cnt;
    int tot = __shfl(inc, 63);
    #pragma unroll
    for (int j=0;j<4;j++){
      u64 msk = mk[j];
      int base = (lane*4+j)*64;
      while (msk && r < NSs){
        int bpos = __ffsll(msk)-1;
        sm.idx_sh[r] = base + bpos;
        msk &= msk-1;
        ++r;
      }
      if (r >= NSs) break;
    }
    int cc = tot < NSs ? tot : NSs;
    int pv = (tot > 0) ? sm.idx_sh[0] : 0;
    if (lane < NSs && lane >= cc) sm.idx_sh[lane] = pv;
  }
  __syncthreads();
}

// ---------------- LN (1024 threads, 32 thr/row) -----------------------------
__device__ __forceinline__ void ln_block1024(SMem& sm, const float* __restrict__ s_,
                                             const float* __restrict__ b_, int t){
  const int s = t >> 5, j = t & 31;
  float v[8];
  float sum = 0.f;
  #pragma unroll
  for (int k=0;k<8;k++){ v[k]=sm.xs[s][j*8+k]; sum += v[k]; }
  #pragma unroll
  for (int m=1;m<32;m<<=1) sum += __shfl_xor(sum, m);
  const float mean = sum * (1.f/256.f);
  float vs = 0.f;
  #pragma unroll
  for (int k=0;k<8;k++){ float d=v[k]-mean; vs += d*d; }
  #pragma unroll
  for (int m=1;m<32;m<<=1) vs += __shfl_xor(vs, m);
  const float rstd = rsqrtf(vs*(1.f/256.f) + LNEPS);
  #pragma unroll
  for (int k=0;k<8;k++){
    int c = j*8+k;
    float y = (v[k]-mean)*rstd*s_[c] + b_[c];
    sm.xs[s][c] = y;
    sm.xn[s][c] = f2bf(y);
  }
}

// ---------------- PE + transformer (1024 threads, 16 waves) -----------------
__device__ void seq_pe_tf(SMem& sm, int b, float ccx, float ccy, float ccz,
    const float* __restrict__ xyz, const float* __restrict__ features,
    const float* __restrict__ featT, int useT,
    const float* __restrict__ pe1w, const float* __restrict__ pe1b,
    const float* __restrict__ bnsc, const float* __restrict__ bnsh,
    const u16* __restrict__ pe2wb, const float* __restrict__ pe2b,
    const u16* __restrict__ ipwb, const float* __restrict__ ipb,
    const u16* __restrict__ opwb, const float* __restrict__ opb,
    const float* __restrict__ ln1s, const float* __restrict__ ln1b,
    const float* __restrict__ ln2s, const float* __restrict__ ln2b,
    const u16* __restrict__ fc1wb, const float* __restrict__ fc1b,
    const u16* __restrict__ fc2wb, const float* __restrict__ fc2b){
  const int t = threadIdx.x, lane = t & 63, wid = t >> 6;
  const int c15 = lane & 15, g4 = lane >> 4;

  if (t < 96){
    int s = t/3, d = t%3;
    float cd = (d==0) ? ccx : ((d==1) ? ccy : ccz);
    sm.gx_sh[s][d] = xyz[((size_t)b*NN + sm.idx_sh[s])*3 + d] - cd;
  }
  if (useT){
    for (int e=t; e<32*NC; e+=NTHR){
      int s=e>>8, c=e&255;
      sm.xs[s][c] = featT[((size_t)b*NN + sm.idx_sh[s])*NC + c];
    }
  } else {
    for (int e=t; e<32*NC; e+=NTHR){
      int s=e>>8, c=e&255;
      sm.xs[s][c] = features[((size_t)b*NC + c)*NN + sm.idx_sh[s]];
    }
  }
  __syncthreads();
  for (int i=t; i<32*128; i+=NTHR){
    int s = i >> 7, o = i & 127;
    float h = pe1w[o*3]*sm.gx_sh[s][0] + pe1w[o*3+1]*sm.gx_sh[s][1] + pe1w[o*3+2]*sm.gx_sh[s][2] + pe1b[o];
    h = h*bnsc[o] + bnsh[o];
    sm.xn[s][o] = f2bf(h > 0.f ? h : 0.f);
  }
  __syncthreads();
  for (int tt=wid; tt<32; tt+=NW){
    int m0 = (tt & 1)*16, n0 = (tt >> 1)*16;
    f32x4 acc = {0.f,0.f,0.f,0.f};
    #pragma unroll
    for (int kk=0; kk<4; kk++){
      s16x8 a = *(const s16x8*)&sm.xn[m0+c15][kk*32 + g4*8];
      s16x8 bb = *(const s16x8*)&pe2wb[(size_t)(n0+c15)*128 + kk*32 + g4*8];
      acc = mfma16(a, bb, acc);
    }
    int col = n0 + c15;
    float bias = pe2b[col];
    #pragma unroll
    for (int r=0;r<4;r++) sm.xs[m0 + g4*4 + r][col] += acc[r] + bias;
  }
  __syncthreads();

  for (int l=0; l<NL; ++l){
    ln_block1024(sm, ln1s + l*NC, ln1b + l*NC, t);
    __syncthreads();
    const u16* Wq = ipwb + (size_t)l*768*NC;
    const float* bq = ipb + l*768;
    for (int tt=wid; tt<96; tt+=NW){
      int m0 = (tt & 1)*16, n0 = (tt >> 1)*16;
      f32x4 acc = {0.f,0.f,0.f,0.f};
      #pragma unroll
      for (int kk=0;kk<8;kk++){
        s16x8 a = *(const s16x8*)&sm.xn[m0+c15][kk*32 + g4*8];
        s16x8 bb = *(const s16x8*)&Wq[(size_t)(n0+c15)*NC + kk*32 + g4*8];
        acc = mfma16(a, bb, acc);
      }
      int col = n0 + c15;
      float bias = bq[col];
      #pragma unroll
      for (int r=0;r<4;r++) sm.qb[m0 + g4*4 + r][col] = f2bf(acc[r] + bias);
    }
    __syncthreads();
    {
      const int h = wid & 3;
      const int mt = (wid >> 2) & 1;
      f32x4 oac[4];
      if (wid < 8){
        f32x4 lac[2];
        #pragma unroll
        for (int nt=0;nt<2;nt++){
          f32x4 acc = {0.f,0.f,0.f,0.f};
          #pragma unroll
          for (int kk=0;kk<2;kk++){
            s16x8 a = *(const s16x8*)&sm.qb[mt*16+c15][h*HDh + kk*32 + g4*8];
            s16x8 bb = *(const s16x8*)&sm.qb[nt*16+c15][256 + h*HDh + kk*32 + g4*8];
            acc = mfma16(a, bb, acc);
          }
          lac[nt] = acc;
        }
        #pragma unroll
        for (int r=0;r<4;r++){
          float v0 = lac[0][r]*0.125f, v1 = lac[1][r]*0.125f;
          float mx = fmaxf(v0, v1);
          #pragma unroll
          for (int m=1;m<16;m<<=1) mx = fmaxf(mx, __shfl_xor(mx, m));
          float e0 = expf(v0-mx), e1 = expf(v1-mx);
          float smm = e0 + e1;
          #pragma unroll
          for (int m=1;m<16;m<<=1) smm += __shfl_xor(smm, m);
          float inv = 1.f/smm;
          int row = mt*16 + g4*4 + r;
          sm.pb[h][row][c15]    = f2bf(e0*inv);
          sm.pb[h][row][16+c15] = f2bf(e1*inv);
        }
        #pragma unroll
        for (int nt=0;nt<4;nt++){
          s16x8 bb;
          #pragma unroll
          for (int e=0;e<8;e++) bb[e] = (short)sm.qb[g4*8+e][512 + h*HDh + nt*16 + c15];
          f32x4 acc = {0.f,0.f,0.f,0.f};
          s16x8 a = *(const s16x8*)&sm.pb[h][mt*16+c15][g4*8];
          oac[nt] = mfma16(a, bb, acc);
        }
      }
      __syncthreads();
      if (wid < 8){
        #pragma unroll
        for (int nt=0;nt<4;nt++)
          #pragma unroll
          for (int r=0;r<4;r++)
            sm.xn[mt*16 + g4*4 + r][h*HDh + nt*16 + c15] = f2bf(oac[nt][r]);
      }
    }
    __syncthreads();
    const u16* Wo = opwb + (size_t)l*NC*NC;
    const float* bo = opb + l*NC;
    for (int tt=wid; tt<32; tt+=NW){
      int m0 = (tt & 1)*16, n0 = (tt >> 1)*16;
      f32x4 acc = {0.f,0.f,0.f,0.f};
      #pragma unroll
      for (int kk=0;kk<8;kk++){
        s16x8 a = *(const s16x8*)&sm.xn[m0+c15][kk*32 + g4*8];
        s16x8 bb = *(const s16x8*)&Wo[(size_t)(n0+c15)*NC + kk*32 + g4*8];
        acc = mfma16(a, bb, acc);
      }
      int col = n0 + c15;
      float bias = bo[col];
      #pragma unroll
      for (int r=0;r<4;r++) sm.xs[m0 + g4*4 + r][col] += acc[r] + bias;
    }
    __syncthreads();
    ln_block1024(sm, ln2s + l*NC, ln2b + l*NC, t);
    __syncthreads();
    const u16* W1 = fc1wb + (size_t)l*NDFF*NC;
    for (int tt=wid; tt<64; tt+=NW){
      int m0 = (tt & 1)*16, n0 = (tt >> 1)*16;
      f32x4 acc = {0.f,0.f,0.f,0.f};
      #pragma unroll
      for (int kk=0;kk<8;kk++){
        s16x8 a = *(const s16x8*)&sm.xn[m0+c15][kk*32 + g4*8];
        s16x8 bb = *(const s16x8*)&W1[(size_t)(n0+c15)*NC + kk*32 + g4*8];
        acc = mfma16(a, bb, acc);
      }
      int col = n0 + c15;
      float bias = fc1b[l*NDFF + col];
      #pragma unroll
      for (int r=0;r<4;r++){
        float v = acc[r] + bias;
        sm.qb[m0 + g4*4 + r][col] = f2bf(v > 0.f ? v : 0.f);
      }
    }
    __syncthreads();
    const u16* W2 = fc2wb + (size_t)l*NC*NDFF;
    for (int tt=wid; tt<32; tt+=NW){
      int m0 = (tt & 1)*16, n0 = (tt >> 1)*16;
      f32x4 acc = {0.f,0.f,0.f,0.f};
      #pragma unroll
      for (int kk=0;kk<16;kk++){
        s16x8 a = *(const s16x8*)&sm.qb[m0+c15][kk*32 + g4*8];
        s16x8 bb = *(const s16x8*)&W2[(size_t)(n0+c15)*NDFF + kk*32 + g4*8];
        acc = mfma16(a, bb, acc);
      }
      int col = n0 + c15;
      float bias = fc2b[l*NC + col];
      #pragma unroll
      for (int r=0;r<4;r++) sm.xs[m0 + g4*4 + r][col] += acc[r] + bias;
    }
    __syncthreads();
  }
}

// ---------------- mega kernel ----------------------------------------------
__global__ __launch_bounds__(NTHR, 4) void k_mega(
    const float* __restrict__ xyz, const float* __restrict__ features,
    const float* __restrict__ featT, int useT,
    u64* __restrict__ cx2, int* __restrict__ first, CtlBlock* ctl,
    const float* __restrict__ pe1w, const float* __restrict__ pe1b,
    const float* __restrict__ bnsc, const float* __restrict__ bnsh,
    const u16* __restrict__ pe2wb, const float* __restrict__ pe2b,
    const u16* __restrict__ ipwb, const float* __restrict__ ipb,
    const u16* __restrict__ opwb, const float* __restrict__ opb,
    const float* __restrict__ ln1s, const float* __restrict__ ln1b,
    const float* __restrict__ ln2s, const float* __restrict__ ln2b,
    const u16* __restrict__ fc1wb, const float* __restrict__ fc1b,
    const u16* __restrict__ fc2wb, const float* __restrict__ fc2b,
    float* __restrict__ out){
  __shared__ SMem sm;
  const int t = threadIdx.x, lane = t & 63, wid = t >> 6;

  if (blockIdx.x < NB){
    fps_run(blockIdx.x, xyz, cx2, ctl, sm);
  } else {
    // phase 1 (light): ballq + first-occurrence arbitration only
    for (;;){
      if (t==0) sm.misc[1] = atomicAdd(&ctl->ctr1, 1);
      __syncthreads();
      int p = sm.misc[1];
      if (p >= NB*NPp) break;
      int b = p >> 11, pp = p & (NPp-1);
      if (t==0){
        while (__hip_atomic_load(&ctl->prog[b], __ATOMIC_RELAXED, __HIP_MEMORY_SCOPE_AGENT) < pp)
          __builtin_amdgcn_s_sleep(32);
        asm volatile("" ::: "memory");
        u64 lo = __hip_atomic_load(&cx2[(size_t)p*2],   __ATOMIC_RELAXED, __HIP_MEMORY_SCOPE_AGENT);
        u64 hi = __hip_atomic_load(&cx2[(size_t)p*2+1], __ATOMIC_RELAXED, __HIP_MEMORY_SCOPE_AGENT);
        sm.misc[4] = (int)(unsigned)(lo & 0xffffffffull);
        sm.misc[5] = (int)(unsigned)(lo >> 32);
        sm.misc[6] = (int)(unsigned)(hi & 0xffffffffull);
      }
      __syncthreads();
      float cx = __int_as_float(sm.misc[4]);
      float cy = __int_as_float(sm.misc[5]);
      float cz = __int_as_float(sm.misc[6]);
      seq_ballq(xyz + (size_t)b*NN*3, cx, cy, cz, sm, t, lane, wid);
      if (t < NSs) atomicMin(&first[b*NN + sm.idx_sh[t]], pp*NSs + t);
      __syncthreads();
    }
  }

  // fenced grid barrier
  __syncthreads();
  if (t==0){
    __builtin_amdgcn_fence(__ATOMIC_RELEASE, "agent");
    __hip_atomic_fetch_add(&ctl->bar, 1, __ATOMIC_RELAXED, __HIP_MEMORY_SCOPE_AGENT);
    while (__hip_atomic_load(&ctl->bar, __ATOMIC_RELAXED, __HIP_MEMORY_SCOPE_AGENT) < NBLK)
      __builtin_amdgcn_s_sleep(8);
    __builtin_amdgcn_fence(__ATOMIC_ACQUIRE, "agent");
  }
  __syncthreads();

  // phase 2: recompute winning sequences, write winning rows to out
  for (;;){
    if (t==0) sm.misc[1] = atomicAdd(&ctl->ctr2, 1);
    __syncthreads();
    int p = sm.misc[1];
    if (p >= NB*NPp) break;
    int b = p >> 11, pp = p & (NPp-1);
    u64 lo = cx2[(size_t)p*2], hi = cx2[(size_t)p*2+1];
    float cx = __int_as_float((int)(unsigned)(lo & 0xffffffffull));
    float cy = __int_as_float((int)(unsigned)(lo >> 32));
    float cz = __int_as_float((int)(unsigned)(hi & 0xffffffffull));
    seq_ballq(xyz + (size_t)b*NN*3, cx, cy, cz, sm, t, lane, wid);
    if (t==0) sm.misc[2] = 0;
    __syncthreads();
    if (t < NSs){
      int pos = pp*NSs + t;
      int f = first[b*NN + sm.idx_sh[t]];
      int w = (f == pos) ? 1 : 0;
      sm.win[t] = w;
      if (w) atomicOr(&sm.misc[2], 1);
    }
    __syncthreads();
    if (!sm.misc[2]) continue;
    seq_pe_tf(sm, b, cx, cy, cz, xyz, features, featT, useT,
              pe1w, pe1b, bnsc, bnsh, pe2wb, pe2b, ipwb, ipb, opwb, opb,
              ln1s, ln1b, ln2s, ln2b, fc1wb, fc1b, fc2wb, fc2b);
    for (int e=t; e<NSs*NC; e+=NTHR){
      int s = e >> 8, c = e & 255;
      if (sm.win[s]) out[((size_t)b*NN + sm.idx_sh[s])*NC + c] = sm.xs[s][c];
    }
    __syncthreads();
  }
}

// ---------------- fill non-winner rows --------------------------------------
__global__ __launch_bounds__(256) void k_outfill_T(const float* __restrict__ featT,
                                                   const int* __restrict__ first,
                                                   float* __restrict__ out){
  const int t = threadIdx.x;
  for (int rr=0; rr<8; ++rr){
    int row = blockIdx.x*8 + rr;
    if (first[row] == LFv)
      out[(size_t)row*NC + t] = featT[(size_t)row*NC + t];
  }
}

__global__ __launch_bounds__(256) void k_outfill_noT(const float* __restrict__ feat,
                                                     const int* __restrict__ first,
                                                     float* __restrict__ out){
  __shared__ float T[32][33];
  const int b = blockIdx.y;
  const int n0 = blockIdx.x*32;
  const int t = threadIdx.x;
  const int tn = t & 31, tc = t >> 5;
  for (int cb=0; cb<NC; cb+=32){
    #pragma unroll
    for (int i=0;i<32;i+=8)
      T[tc+i][tn] = feat[((size_t)b*NC + cb+tc+i)*NN + n0+tn];
    __syncthreads();
    #pragma unroll
    for (int i=0;i<32;i+=8){
      int n = n0 + tc + i;
      if (first[b*NN+n] == LFv)
        out[((size_t)b*NN + n)*NC + cb+tn] = T[tn][tc+i];
    }
    __syncthreads();
  }
}

extern "C" void kernel_launch(void* const* d_in, const int* in_sizes, int n_in,
                              void* d_out, int out_size, void* d_ws, size_t ws_size,
                              hipStream_t stream){
  const float* xyz   = (const float*)d_in[0];
  const float* feat  = (const float*)d_in[1];
  const float* pe1w  = (const float*)d_in[2];
  const float* pe1b  = (const float*)d_in[3];
  const float* bng   = (const float*)d_in[4];
  const float* bnb   = (const float*)d_in[5];
  const float* bnm   = (const float*)d_in[6];
  const float* bnv   = (const float*)d_in[7];
  const float* pe2w  = (const float*)d_in[8];
  const float* pe2b  = (const float*)d_in[9];
  const float* ipw   = (const float*)d_in[10];
  const float* ipb   = (const float*)d_in[11];
  const float* opw   = (const float*)d_in[12];
  const float* opb   = (const float*)d_in[13];
  const float* ln1s  = (const float*)d_in[14];
  const float* ln1b  = (const float*)d_in[15];
  const float* ln2s  = (const float*)d_in[16];
  const float* ln2b  = (const float*)d_in[17];
  const float* fc1w  = (const float*)d_in[18];
  const float* fc1b  = (const float*)d_in[19];
  const float* fc2w  = (const float*)d_in[20];
  const float* fc2b  = (const float*)d_in[21];
  float* out = (float*)d_out;

  char* ws = (char*)d_ws;
  size_t off = 0;
  auto alloc = [&](size_t bytes)->void*{
    void* p = ws + off;
    off = (off + bytes + 255) & ~(size_t)255;
    return p;
  };
  u64*   cx2     = (u64*)  alloc((size_t)NB*NPp*2*8);
  int*   first   = (int*)  alloc((size_t)NB*NN*4);
  CtlBlock* ctl  = (CtlBlock*)alloc(sizeof(CtlBlock));
  float* bnsc    = (float*)alloc(128*4);
  float* bnsh    = (float*)alloc(128*4);
  u16*   ipwb    = (u16*)  alloc((size_t)NL*768*NC*2);
  u16*   opwb    = (u16*)  alloc((size_t)NL*NC*NC*2);
  u16*   fc1wb   = (u16*)  alloc((size_t)NL*NDFF*NC*2);
  u16*   fc2wb   = (u16*)  alloc((size_t)NL*NC*NDFF*2);
  u16*   pe2wb   = (u16*)  alloc((size_t)NC*128*2);
  int useT = (off + (size_t)NB*NN*NC*4 <= ws_size) ? 1 : 0;
  float* featT = (float*)(useT ? alloc((size_t)NB*NN*NC*4) : (void*)ws);

  k_prep<<<512, 256, 0, stream>>>(ipw, opw, fc1w, fc2w, pe2w, bng, bnb, bnm, bnv,
                                  ipwb, opwb, fc1wb, fc2wb, pe2wb, bnsc, bnsh, first, ctl);
  if (useT)
    k_featT<<<dim3(NN/32, NB), 256, 0, stream>>>(feat, featT);

  const float* featT_c = featT;
  void* kargs[] = {
    (void*)&xyz, (void*)&feat, (void*)&featT_c, (void*)&useT,
    (void*)&cx2, (void*)&first, (void*)&ctl,
    (void*)&pe1w, (void*)&pe1b, (void*)&bnsc, (void*)&bnsh,
    (void*)&pe2wb, (void*)&pe2b, (void*)&ipwb, (void*)&ipb,
    (void*)&opwb, (void*)&opb, (void*)&ln1s, (void*)&ln1b,
    (void*)&ln2s, (void*)&ln2b, (void*)&fc1wb, (void*)&fc1b,
    (void*)&fc2wb, (void*)&fc2b, (void*)&out };
  hipLaunchCooperativeKernel((void*)k_mega, dim3(NBLK), dim3(NTHR), kargs, 0, stream);

  if (useT)
    k_outfill_T<<<(NB*NN)/8, 256, 0, stream>>>(featT, first, out);
  else
    k_outfill_noT<<<dim3(NN/32, NB), 256, 0, stream>>>(feat, first, out);
  (void)in_sizes; (void)n_in; (void)out_size;
}

// Round 10
// 4692.759 us; speedup vs baseline: 1.2224x; 1.2173x over previous
//
#include <hip/hip_runtime.h>

#define NB 2
#define NN 16384
#define NC 256
#define NPp 2048
#define NSs 32
#define NH 4
#define HDh 64
#define NL 2
#define NDFF 512
#define LFv (NPp*NSs)
#define LNEPS 1e-5f
#define NBLK 256
#define NTHR 512
#define NW 8

typedef short s16x8 __attribute__((ext_vector_type(8)));
typedef float f32x4 __attribute__((ext_vector_type(4)));
typedef float f32x2 __attribute__((ext_vector_type(2)));
typedef unsigned short u16;
typedef unsigned long long u64;

struct CtlBlock { int ctr1; int ctr2; int bar; };

__device__ __forceinline__ u16 f2bf(float f){
  unsigned u = __float_as_uint(f);
  u += 0x7fffu + ((u>>16)&1u);
  return (u16)(u>>16);
}

__device__ __forceinline__ f32x4 mfma16(s16x8 a, s16x8 b, f32x4 c){
  return __builtin_amdgcn_mfma_f32_16x16x32_bf16(a, b, c, 0, 0, 0);
}

__device__ __forceinline__ f32x2 pk_add(f32x2 a, f32x2 b){
  f32x2 d; asm("v_pk_add_f32 %0, %1, %2" : "=v"(d) : "v"(a), "v"(b)); return d;
}
__device__ __forceinline__ f32x2 pk_mul(f32x2 a, f32x2 b){
  f32x2 d; asm("v_pk_mul_f32 %0, %1, %2" : "=v"(d) : "v"(a), "v"(b)); return d;
}

#define DPP_FMAX(v, ctrl) do { \
  int _iv = __float_as_int(v); \
  int _sh = __builtin_amdgcn_update_dpp(_iv, _iv, (ctrl), 0xF, 0xF, false); \
  (v) = fmaxf((v), __int_as_float(_sh)); \
} while(0)

#define DPP_IMIN(v, ctrl) do { \
  int _sh = __builtin_amdgcn_update_dpp((v), (v), (ctrl), 0xF, 0xF, false); \
  (v) = (_sh < (v)) ? _sh : (v); \
} while(0)

struct SMem {
  u64  masks[256];
  u64  keybuf[4];
  float wvc[2][NW][4];
  float cxbuf[8][4];
  float xs[32][260];
  u16  xn[32][264];
  u16  qb[32][776];
  u16  pb[NH][32][40];
  int  idx_sh[32];
  float gx_sh[32][3];
  int  misc[16];
  int  win[32];
};

// ---------------- prep ------------------------------------------------------
__global__ void k_prep(const float* __restrict__ ipw, const float* __restrict__ opw,
                       const float* __restrict__ fc1w, const float* __restrict__ fc2w,
                       const float* __restrict__ pe2w,
                       const float* __restrict__ bng, const float* __restrict__ bnb,
                       const float* __restrict__ bnm, const float* __restrict__ bnv,
                       u16* ipwb, u16* opwb, u16* fc1wb, u16* fc2wb, u16* pe2wb,
                       float* bnsc, float* bnsh, int* first, int* rdy, CtlBlock* ctl){
  const int i0 = blockIdx.x*blockDim.x + threadIdx.x;
  const int stride = gridDim.x*blockDim.x;
  for (int i=i0; i<NL*768*NC; i+=stride) ipwb[i] = f2bf(ipw[i]);
  for (int i=i0; i<NL*NC*NC; i+=stride)  opwb[i] = f2bf(opw[i]);
  for (int i=i0; i<NL*NDFF*NC; i+=stride) fc1wb[i] = f2bf(fc1w[i]);
  for (int i=i0; i<NL*NC*NDFF; i+=stride) fc2wb[i] = f2bf(fc2w[i]);
  for (int i=i0; i<NC*128; i+=stride)    pe2wb[i] = f2bf(pe2w[i]);
  for (int i=i0; i<NB*NN; i+=stride)     first[i] = LFv;
  for (int i=i0; i<NB*NPp; i+=stride)    rdy[i] = 0;
  for (int i=i0; i<128; i+=stride){
    float sc = bng[i]*rsqrtf(bnv[i]+LNEPS);
    bnsc[i] = sc; bnsh[i] = bnb[i] - bnm[i]*sc;
  }
  if (i0 == 0){ ctl->ctr1 = 0; ctl->ctr2 = 0; ctl->bar = 0; }
}

// ---------------- featT -----------------------------------------------------
__global__ __launch_bounds__(256) void k_featT(const float* __restrict__ feat,
                                               float* __restrict__ featT){
  __shared__ float T[32][33];
  const int b = blockIdx.y;
  const int n0 = blockIdx.x*32;
  const int t = threadIdx.x;
  const int tn = t & 31, tc = t >> 5;
  for (int cb=0; cb<NC; cb+=32){
    #pragma unroll
    for (int i=0;i<32;i+=8)
      T[tc+i][tn] = feat[((size_t)b*NC + cb+tc+i)*NN + n0+tn];
    __syncthreads();
    #pragma unroll
    for (int i=0;i<32;i+=8)
      featT[((size_t)b*NN + n0+tc+i)*NC + cb+tn] = T[tn][tc+i];
    __syncthreads();
  }
}

#define SELC(S) case S: scx = px2[(S)>>1][(S)&1]; scy = py2[(S)>>1][(S)&1]; scz = pz2[(S)>>1][(S)&1]; break;

// ---------------- FPS role: 512 thr, 32 pts/thread, register-resident -------
__device__ void fps_run(int b, const float* __restrict__ xyz, u64* __restrict__ cx2,
                        int* __restrict__ rdy, SMem& sm){
#pragma clang fp contract(off)
  const int t = threadIdx.x;
  const int lane = t & 63, wid = t >> 6;
  const float* xb = xyz + (size_t)b*NN*3;
  f32x2 px2[16], py2[16], pz2[16], dd2[16];
  #pragma unroll
  for (int m=0;m<16;m++){
    int i0 = t + (2*m)*NTHR, i1 = t + (2*m+1)*NTHR;
    px2[m] = f32x2{xb[i0*3],   xb[i1*3]};
    py2[m] = f32x2{xb[i0*3+1], xb[i1*3+1]};
    pz2[m] = f32x2{xb[i0*3+2], xb[i1*3+2]};
    dd2[m] = f32x2{1e10f, 1e10f};
  }
  if (t < 4) sm.keybuf[t] = 0ull;
  float ncx, ncy, ncz;
  {
    float wx = xb[0], wy = xb[1], wz = xb[2];
    ncx=-wx; ncy=-wy; ncz=-wz;
    if (t==0){ sm.cxbuf[0][0]=wx; sm.cxbuf[0][1]=wy; sm.cxbuf[0][2]=wz; }
  }
  __syncthreads();
  for (int step=1; step<NPp; ++step){
    const f32x2 ncx2={ncx,ncx}, ncy2={ncy,ncy}, ncz2={ncz,ncz};
    float bestv = -1.f;
    #pragma unroll
    for (int m=0;m<16;m++){
      f32x2 dx = pk_add(px2[m], ncx2);
      f32x2 dy = pk_add(py2[m], ncy2);
      f32x2 dz = pk_add(pz2[m], ncz2);
      f32x2 s  = pk_add(pk_add(pk_mul(dx,dx), pk_mul(dy,dy)), pk_mul(dz,dz));
      dd2[m].x = fminf(dd2[m].x, s.x);
      dd2[m].y = fminf(dd2[m].y, s.y);
      bestv = fmaxf(fmaxf(bestv, dd2[m].x), dd2[m].y);
    }
    float M = bestv;
    DPP_FMAX(M, 0x111); DPP_FMAX(M, 0x112); DPP_FMAX(M, 0x114); DPP_FMAX(M, 0x118);
    DPP_FMAX(M, 0x142); DPP_FMAX(M, 0x143);
    const int Mi = __builtin_amdgcn_readlane(__float_as_int(M), 63);
    const float Ms = __int_as_float(Mi);
    int li = 0x7fffffff;
    #pragma unroll
    for (int m=15;m>=0;m--){
      if (dd2[m].y == Ms) li = t + (2*m+1)*NTHR;
      if (dd2[m].x == Ms) li = t + (2*m)*NTHR;
    }
    DPP_IMIN(li, 0x111); DPP_IMIN(li, 0x112); DPP_IMIN(li, 0x114); DPP_IMIN(li, 0x118);
    DPP_IMIN(li, 0x142); DPP_IMIN(li, 0x143);
    const int li63 = __builtin_amdgcn_readlane(li, 63);
    const int kb = step & 3, cb = step & 1;
    if (lane==0){
      u64 key = ((u64)(unsigned)Mi << 32) | (unsigned)(0x7fffffff - li63);
      atomicMax(&sm.keybuf[kb], key);
    }
    {
      const int slot = li63 >> 9;                // wave-uniform
      float scx=0.f, scy=0.f, scz=0.f;
      switch(slot){
        SELC(0) SELC(1) SELC(2) SELC(3) SELC(4) SELC(5) SELC(6) SELC(7)
        SELC(8) SELC(9) SELC(10) SELC(11) SELC(12) SELC(13) SELC(14) SELC(15)
        SELC(16) SELC(17) SELC(18) SELC(19) SELC(20) SELC(21) SELC(22) SELC(23)
        SELC(24) SELC(25) SELC(26) SELC(27) SELC(28) SELC(29) SELC(30) SELC(31)
        default: break;
      }
      if (t == (li63 & (NTHR-1))){               // owner thread of this wave
        sm.wvc[cb][wid][0]=scx; sm.wvc[cb][wid][1]=scy; sm.wvc[cb][wid][2]=scz;
      }
    }
    __syncthreads();                             // the ONLY barrier per step
    const u64 kk = sm.keybuf[kb];
    const int widx = 0x7fffffff - (int)(unsigned)(kk & 0xffffffffull);
    const int wv = (widx & (NTHR-1)) >> 6;
    const float bx = sm.wvc[cb][wv][0];
    const float by = sm.wvc[cb][wv][1];
    const float bz = sm.wvc[cb][wv][2];
    ncx=-bx; ncy=-by; ncz=-bz;
    if (t==0){
      sm.cxbuf[step & 7][0]=bx; sm.cxbuf[step & 7][1]=by; sm.cxbuf[step & 7][2]=bz;
      sm.keybuf[(step+2) & 3] = 0ull;            // reset at distance 2 (race-free)
      if ((step & 7) == 7){
        int s0 = step - 7;
        #pragma unroll
        for (int j=0;j<8;j++){
          float fx=sm.cxbuf[j][0], fy=sm.cxbuf[j][1], fz=sm.cxbuf[j][2];
          u64 lo = ((u64)__float_as_uint(fy) << 32) | __float_as_uint(fx);
          u64 hi = (u64)__float_as_uint(fz);
          size_t pb2 = (size_t)(b*NPp + s0 + j)*2;
          __hip_atomic_store(&cx2[pb2],   lo, __ATOMIC_RELAXED, __HIP_MEMORY_SCOPE_AGENT);
          __hip_atomic_store(&cx2[pb2+1], hi, __ATOMIC_RELAXED, __HIP_MEMORY_SCOPE_AGENT);
        }
        asm volatile("s_waitcnt vmcnt(0)" ::: "memory");   // data visible before flags
        #pragma unroll
        for (int j=0;j<8;j++)
          __hip_atomic_store(&rdy[b*NPp + s0 + j], 1, __ATOMIC_RELAXED, __HIP_MEMORY_SCOPE_AGENT);
      }
    }
  }
}

// ---------------- inline ball query (512 threads) ---------------------------
__device__ void seq_ballq(const float* __restrict__ xb, float cx, float cy, float cz,
                          SMem& sm, int t, int lane, int wid){
#pragma clang fp contract(off)
  for (int it=0; it<32; ++it){
    int cid = wid*32 + it;
    int i = cid*64 + lane;
    float dx=xb[i*3]-cx, dy=xb[i*3+1]-cy, dz=xb[i*3+2]-cz;
    float d2=(dx*dx+dy*dy)+dz*dz;
    u64 m = __ballot(d2 < 1.0f);
    if (lane==0) sm.masks[cid] = m;
  }
  __syncthreads();
  if (wid==0){
    u64 mk[4]; int cnt=0;
    #pragma unroll
    for (int j=0;j<4;j++){ mk[j]=sm.masks[lane*4+j]; cnt += __popcll(mk[j]); }
    int inc = cnt;
    #pragma unroll
    for (int ofs=1; ofs<64; ofs<<=1){
      int v = __shfl_up(inc, ofs);
      if (lane >= ofs) inc += v;
    }
    int r = inc - cnt;
    int tot = __shfl(inc, 63);
    #pragma unroll
    for (int j=0;j<4;j++){
      u64 msk = mk[j];
      int base = (lane*4+j)*64;
      while (msk && r < NSs){
        int bpos = __ffsll(msk)-1;
        sm.idx_sh[r] = base + bpos;
        msk &= msk-1;
        ++r;
      }
      if (r >= NSs) break;
    }
    int cc = tot < NSs ? tot : NSs;
    int pv = (tot > 0) ? sm.idx_sh[0] : 0;
    if (lane < NSs && lane >= cc) sm.idx_sh[lane] = pv;
  }
  __syncthreads();
}

// ---------------- LN (512 threads, 16 thr/row) ------------------------------
__device__ __forceinline__ void ln_block512(SMem& sm, const float* __restrict__ s_,
                                            const float* __restrict__ b_, int t){
  const int s = t >> 4, j = t & 15;
  float v[16];
  float sum = 0.f;
  #pragma unroll
  for (int k=0;k<16;k++){ v[k]=sm.xs[s][j*16+k]; sum += v[k]; }
  #pragma unroll
  for (int m=1;m<16;m<<=1) sum += __shfl_xor(sum, m);
  const float mean = sum * (1.f/256.f);
  float vs = 0.f;
  #pragma unroll
  for (int k=0;k<16;k++){ float d=v[k]-mean; vs += d*d; }
  #pragma unroll
  for (int m=1;m<16;m<<=1) vs += __shfl_xor(vs, m);
  const float rstd = rsqrtf(vs*(1.f/256.f) + LNEPS);
  #pragma unroll
  for (int k=0;k<16;k++){
    int c = j*16+k;
    float y = (v[k]-mean)*rstd*s_[c] + b_[c];
    sm.xs[s][c] = y;
    sm.xn[s][c] = f2bf(y);
  }
}

// ---------------- PE + transformer (512 threads, 8 waves) -------------------
__device__ void seq_pe_tf(SMem& sm, int b, float ccx, float ccy, float ccz,
    const float* __restrict__ xyz, const float* __restrict__ features,
    const float* __restrict__ featT, int useT,
    const float* __restrict__ pe1w, const float* __restrict__ pe1b,
    const float* __restrict__ bnsc, const float* __restrict__ bnsh,
    const u16* __restrict__ pe2wb, const float* __restrict__ pe2b,
    const u16* __restrict__ ipwb, const float* __restrict__ ipb,
    const u16* __restrict__ opwb, const float* __restrict__ opb,
    const float* __restrict__ ln1s, const float* __restrict__ ln1b,
    const float* __restrict__ ln2s, const float* __restrict__ ln2b,
    const u16* __restrict__ fc1wb, const float* __restrict__ fc1b,
    const u16* __restrict__ fc2wb, const float* __restrict__ fc2b){
  const int t = threadIdx.x, lane = t & 63, wid = t >> 6;
  const int c15 = lane & 15, g4 = lane >> 4;

  if (t < 96){
    int s = t/3, d = t%3;
    float cd = (d==0) ? ccx : ((d==1) ? ccy : ccz);
    sm.gx_sh[s][d] = xyz[((size_t)b*NN + sm.idx_sh[s])*3 + d] - cd;
  }
  if (useT){
    for (int e=t; e<32*NC; e+=NTHR){
      int s=e>>8, c=e&255;
      sm.xs[s][c] = featT[((size_t)b*NN + sm.idx_sh[s])*NC + c];
    }
  } else {
    for (int e=t; e<32*NC; e+=NTHR){
      int s=e>>8, c=e&255;
      sm.xs[s][c] = features[((size_t)b*NC + c)*NN + sm.idx_sh[s]];
    }
  }
  __syncthreads();
  for (int i=t; i<32*128; i+=NTHR){
    int s = i >> 7, o = i & 127;
    float h = pe1w[o*3]*sm.gx_sh[s][0] + pe1w[o*3+1]*sm.gx_sh[s][1] + pe1w[o*3+2]*sm.gx_sh[s][2] + pe1b[o];
    h = h*bnsc[o] + bnsh[o];
    sm.xn[s][o] = f2bf(h > 0.f ? h : 0.f);
  }
  __syncthreads();
  for (int tt=wid; tt<32; tt+=NW){
    int m0 = (tt & 1)*16, n0 = (tt >> 1)*16;
    f32x4 acc = {0.f,0.f,0.f,0.f};
    #pragma unroll
    for (int kk=0; kk<4; kk++){
      s16x8 a = *(const s16x8*)&sm.xn[m0+c15][kk*32 + g4*8];
      s16x8 bb = *(const s16x8*)&pe2wb[(size_t)(n0+c15)*128 + kk*32 + g4*8];
      acc = mfma16(a, bb, acc);
    }
    int col = n0 + c15;
    float bias = pe2b[col];
    #pragma unroll
    for (int r=0;r<4;r++) sm.xs[m0 + g4*4 + r][col] += acc[r] + bias;
  }
  __syncthreads();

  for (int l=0; l<NL; ++l){
    ln_block512(sm, ln1s + l*NC, ln1b + l*NC, t);
    __syncthreads();
    const u16* Wq = ipwb + (size_t)l*768*NC;
    const float* bq = ipb + l*768;
    for (int tt=wid; tt<96; tt+=NW){
      int m0 = (tt & 1)*16, n0 = (tt >> 1)*16;
      f32x4 acc = {0.f,0.f,0.f,0.f};
      #pragma unroll
      for (int kk=0;kk<8;kk++){
        s16x8 a = *(const s16x8*)&sm.xn[m0+c15][kk*32 + g4*8];
        s16x8 bb = *(const s16x8*)&Wq[(size_t)(n0+c15)*NC + kk*32 + g4*8];
        acc = mfma16(a, bb, acc);
      }
      int col = n0 + c15;
      float bias = bq[col];
      #pragma unroll
      for (int r=0;r<4;r++) sm.qb[m0 + g4*4 + r][col] = f2bf(acc[r] + bias);
    }
    __syncthreads();
    {
      const int h = wid & 3;
      const int mt = wid >> 2;
      f32x4 lac[2];
      #pragma unroll
      for (int nt=0;nt<2;nt++){
        f32x4 acc = {0.f,0.f,0.f,0.f};
        #pragma unroll
        for (int kk=0;kk<2;kk++){
          s16x8 a = *(const s16x8*)&sm.qb[mt*16+c15][h*HDh + kk*32 + g4*8];
          s16x8 bb = *(const s16x8*)&sm.qb[nt*16+c15][256 + h*HDh + kk*32 + g4*8];
          acc = mfma16(a, bb, acc);
        }
        lac[nt] = acc;
      }
      #pragma unroll
      for (int r=0;r<4;r++){
        float v0 = lac[0][r]*0.125f, v1 = lac[1][r]*0.125f;
        float mx = fmaxf(v0, v1);
        #pragma unroll
        for (int m=1;m<16;m<<=1) mx = fmaxf(mx, __shfl_xor(mx, m));
        float e0 = expf(v0-mx), e1 = expf(v1-mx);
        float smm = e0 + e1;
        #pragma unroll
        for (int m=1;m<16;m<<=1) smm += __shfl_xor(smm, m);
        float inv = 1.f/smm;
        int row = mt*16 + g4*4 + r;
        sm.pb[h][row][c15]    = f2bf(e0*inv);
        sm.pb[h][row][16+c15] = f2bf(e1*inv);
      }
      f32x4 oac[4];
      #pragma unroll
      for (int nt=0;nt<4;nt++){
        s16x8 bb;
        #pragma unroll
        for (int e=0;e<8;e++) bb[e] = (short)sm.qb[g4*8+e][512 + h*HDh + nt*16 + c15];
        f32x4 acc = {0.f,0.f,0.f,0.f};
        s16x8 a = *(const s16x8*)&sm.pb[h][mt*16+c15][g4*8];
        oac[nt] = mfma16(a, bb, acc);
      }
      __syncthreads();
      #pragma unroll
      for (int nt=0;nt<4;nt++)
        #pragma unroll
        for (int r=0;r<4;r++)
          sm.xn[mt*16 + g4*4 + r][h*HDh + nt*16 + c15] = f2bf(oac[nt][r]);
    }
    __syncthreads();
    const u16* Wo = opwb + (size_t)l*NC*NC;
    const float* bo = opb + l*NC;
    for (int tt=wid; tt<32; tt+=NW){
      int m0 = (tt & 1)*16, n0 = (tt >> 1)*16;
      f32x4 acc = {0.f,0.f,0.f,0.f};
      #pragma unroll
      for (int kk=0;kk<8;kk++){
        s16x8 a = *(const s16x8*)&sm.xn[m0+c15][kk*32 + g4*8];
        s16x8 bb = *(const s16x8*)&Wo[(size_t)(n0+c15)*NC + kk*32 + g4*8];
        acc = mfma16(a, bb, acc);
      }
      int col = n0 + c15;
      float bias = bo[col];
      #pragma unroll
      for (int r=0;r<4;r++) sm.xs[m0 + g4*4 + r][col] += acc[r] + bias;
    }
    __syncthreads();
    ln_block512(sm, ln2s + l*NC, ln2b + l*NC, t);
    __syncthreads();
    const u16* W1 = fc1wb + (size_t)l*NDFF*NC;
    for (int tt=wid; tt<64; tt+=NW){
      int m0 = (tt & 1)*16, n0 = (tt >> 1)*16;
      f32x4 acc = {0.f,0.f,0.f,0.f};
      #pragma unroll
      for (int kk=0;kk<8;kk++){
        s16x8 a = *(const s16x8*)&sm.xn[m0+c15][kk*32 + g4*8];
        s16x8 bb = *(const s16x8*)&W1[(size_t)(n0+c15)*NC + kk*32 + g4*8];
        acc = mfma16(a, bb, acc);
      }
      int col = n0 + c15;
      float bias = fc1b[l*NDFF + col];
      #pragma unroll
      for (int r=0;r<4;r++){
        float v = acc[r] + bias;
        sm.qb[m0 + g4*4 + r][col] = f2bf(v > 0.f ? v : 0.f);
      }
    }
    __syncthreads();
    const u16* W2 = fc2wb + (size_t)l*NC*NDFF;
    for (int tt=wid; tt<32; tt+=NW){
      int m0 = (tt & 1)*16, n0 = (tt >> 1)*16;
      f32x4 acc = {0.f,0.f,0.f,0.f};
      #pragma unroll
      for (int kk=0;kk<16;kk++){
        s16x8 a = *(const s16x8*)&sm.qb[m0+c15][kk*32 + g4*8];
        s16x8 bb = *(const s16x8*)&W2[(size_t)(n0+c15)*NDFF + kk*32 + g4*8];
        acc = mfma16(a, bb, acc);
      }
      int col = n0 + c15;
      float bias = fc2b[l*NC + col];
      #pragma unroll
      for (int r=0;r<4;r++) sm.xs[m0 + g4*4 + r][col] += acc[r] + bias;
    }
    __syncthreads();
  }
}

// ---------------- mega kernel ----------------------------------------------
__global__ __launch_bounds__(NTHR, 2) void k_mega(
    const float* __restrict__ xyz, const float* __restrict__ features,
    const float* __restrict__ featT, int useT,
    u64* __restrict__ cx2, int* __restrict__ rdy, int* __restrict__ first, CtlBlock* ctl,
    const float* __restrict__ pe1w, const float* __restrict__ pe1b,
    const float* __restrict__ bnsc, const float* __restrict__ bnsh,
    const u16* __restrict__ pe2wb, const float* __restrict__ pe2b,
    const u16* __restrict__ ipwb, const float* __restrict__ ipb,
    const u16* __restrict__ opwb, const float* __restrict__ opb,
    const float* __restrict__ ln1s, const float* __restrict__ ln1b,
    const float* __restrict__ ln2s, const float* __restrict__ ln2b,
    const u16* __restrict__ fc1wb, const float* __restrict__ fc1b,
    const u16* __restrict__ fc2wb, const float* __restrict__ fc2b,
    float* __restrict__ out){
  __shared__ SMem sm;
  const int t = threadIdx.x, lane = t & 63, wid = t >> 6;

  if (blockIdx.x < NB){
    fps_run(blockIdx.x, xyz, cx2, rdy, sm);
  } else {
    // phase 1 (light): ballq + first-occurrence arbitration, per-p flag pacing
    for (;;){
      if (t==0) sm.misc[1] = atomicAdd(&ctl->ctr1, 1);
      __syncthreads();
      int p = sm.misc[1];
      if (p >= NB*NPp) break;
      int b = p >> 11, pp = p & (NPp-1);
      if (t==0){
        while (!__hip_atomic_load(&rdy[p], __ATOMIC_RELAXED, __HIP_MEMORY_SCOPE_AGENT))
          __builtin_amdgcn_s_sleep(16);
        asm volatile("" ::: "memory");
        u64 lo = __hip_atomic_load(&cx2[(size_t)p*2],   __ATOMIC_RELAXED, __HIP_MEMORY_SCOPE_AGENT);
        u64 hi = __hip_atomic_load(&cx2[(size_t)p*2+1], __ATOMIC_RELAXED, __HIP_MEMORY_SCOPE_AGENT);
        sm.misc[4] = (int)(unsigned)(lo & 0xffffffffull);
        sm.misc[5] = (int)(unsigned)(lo >> 32);
        sm.misc[6] = (int)(unsigned)(hi & 0xffffffffull);
      }
      __syncthreads();
      float cx = __int_as_float(sm.misc[4]);
      float cy = __int_as_float(sm.misc[5]);
      float cz = __int_as_float(sm.misc[6]);
      seq_ballq(xyz + (size_t)b*NN*3, cx, cy, cz, sm, t, lane, wid);
      if (t < NSs) atomicMin(&first[b*NN + sm.idx_sh[t]], pp*NSs + t);
      __syncthreads();
    }
  }

  // fenced grid barrier
  __syncthreads();
  if (t==0){
    __builtin_amdgcn_fence(__ATOMIC_RELEASE, "agent");
    __hip_atomic_fetch_add(&ctl->bar, 1, __ATOMIC_RELAXED, __HIP_MEMORY_SCOPE_AGENT);
    while (__hip_atomic_load(&ctl->bar, __ATOMIC_RELAXED, __HIP_MEMORY_SCOPE_AGENT) < NBLK)
      __builtin_amdgcn_s_sleep(8);
    __builtin_amdgcn_fence(__ATOMIC_ACQUIRE, "agent");
  }
  __syncthreads();

  // phase 2: recompute winning sequences, write winning rows to out
  for (;;){
    if (t==0) sm.misc[1] = atomicAdd(&ctl->ctr2, 1);
    __syncthreads();
    int p = sm.misc[1];
    if (p >= NB*NPp) break;
    int b = p >> 11, pp = p & (NPp-1);
    u64 lo = cx2[(size_t)p*2], hi = cx2[(size_t)p*2+1];
    float cx = __int_as_float((int)(unsigned)(lo & 0xffffffffull));
    float cy = __int_as_float((int)(unsigned)(lo >> 32));
    float cz = __int_as_float((int)(unsigned)(hi & 0xffffffffull));
    seq_ballq(xyz + (size_t)b*NN*3, cx, cy, cz, sm, t, lane, wid);
    if (t==0) sm.misc[2] = 0;
    __syncthreads();
    if (t < NSs){
      int pos = pp*NSs + t;
      int f = first[b*NN + sm.idx_sh[t]];
      int w = (f == pos) ? 1 : 0;
      sm.win[t] = w;
      if (w) atomicOr(&sm.misc[2], 1);
    }
    __syncthreads();
    if (!sm.misc[2]) continue;
    seq_pe_tf(sm, b, cx, cy, cz, xyz, features, featT, useT,
              pe1w, pe1b, bnsc, bnsh, pe2wb, pe2b, ipwb, ipb, opwb, opb,
              ln1s, ln1b, ln2s, ln2b, fc1wb, fc1b, fc2wb, fc2b);
    for (int e=t; e<NSs*NC; e+=NTHR){
      int s = e >> 8, c = e & 255;
      if (sm.win[s]) out[((size_t)b*NN + sm.idx_sh[s])*NC + c] = sm.xs[s][c];
    }
    __syncthreads();
  }
}

// ---------------- fill non-winner rows --------------------------------------
__global__ __launch_bounds__(256) void k_outfill_T(const float* __restrict__ featT,
                                                   const int* __restrict__ first,
                                                   float* __restrict__ out){
  const int t = threadIdx.x;
  for (int rr=0; rr<8; ++rr){
    int row = blockIdx.x*8 + rr;
    if (first[row] == LFv)
      out[(size_t)row*NC + t] = featT[(size_t)row*NC + t];
  }
}

__global__ __launch_bounds__(256) void k_outfill_noT(const float* __restrict__ feat,
                                                     const int* __restrict__ first,
                                                     float* __restrict__ out){
  __shared__ float T[32][33];
  const int b = blockIdx.y;
  const int n0 = blockIdx.x*32;
  const int t = threadIdx.x;
  const int tn = t & 31, tc = t >> 5;
  for (int cb=0; cb<NC; cb+=32){
    #pragma unroll
    for (int i=0;i<32;i+=8)
      T[tc+i][tn] = feat[((size_t)b*NC + cb+tc+i)*NN + n0+tn];
    __syncthreads();
    #pragma unroll
    for (int i=0;i<32;i+=8){
      int n = n0 + tc + i;
      if (first[b*NN+n] == LFv)
        out[((size_t)b*NN + n)*NC + cb+tn] = T[tn][tc+i];
    }
    __syncthreads();
  }
}

extern "C" void kernel_launch(void* const* d_in, const int* in_sizes, int n_in,
                              void* d_out, int out_size, void* d_ws, size_t ws_size,
                              hipStream_t stream){
  const float* xyz   = (const float*)d_in[0];
  const float* feat  = (const float*)d_in[1];
  const float* pe1w  = (const float*)d_in[2];
  const float* pe1b  = (const float*)d_in[3];
  const float* bng   = (const float*)d_in[4];
  const float* bnb   = (const float*)d_in[5];
  const float* bnm   = (const float*)d_in[6];
  const float* bnv   = (const float*)d_in[7];
  const float* pe2w  = (const float*)d_in[8];
  const float* pe2b  = (const float*)d_in[9];
  const float* ipw   = (const float*)d_in[10];
  const float* ipb   = (const float*)d_in[11];
  const float* opw   = (const float*)d_in[12];
  const float* opb   = (const float*)d_in[13];
  const float* ln1s  = (const float*)d_in[14];
  const float* ln1b  = (const float*)d_in[15];
  const float* ln2s  = (const float*)d_in[16];
  const float* ln2b  = (const float*)d_in[17];
  const float* fc1w  = (const float*)d_in[18];
  const float* fc1b  = (const float*)d_in[19];
  const float* fc2w  = (const float*)d_in[20];
  const float* fc2b  = (const float*)d_in[21];
  float* out = (float*)d_out;

  char* ws = (char*)d_ws;
  size_t off = 0;
  auto alloc = [&](size_t bytes)->void*{
    void* p = ws + off;
    off = (off + bytes + 255) & ~(size_t)255;
    return p;
  };
  u64*   cx2     = (u64*)  alloc((size_t)NB*NPp*2*8);
  int*   rdy     = (int*)  alloc((size_t)NB*NPp*4);
  int*   first   = (int*)  alloc((size_t)NB*NN*4);
  CtlBlock* ctl  = (CtlBlock*)alloc(sizeof(CtlBlock));
  float* bnsc    = (float*)alloc(128*4);
  float* bnsh    = (float*)alloc(128*4);
  u16*   ipwb    = (u16*)  alloc((size_t)NL*768*NC*2);
  u16*   opwb    = (u16*)  alloc((size_t)NL*NC*NC*2);
  u16*   fc1wb   = (u16*)  alloc((size_t)NL*NDFF*NC*2);
  u16*   fc2wb   = (u16*)  alloc((size_t)NL*NC*NDFF*2);
  u16*   pe2wb   = (u16*)  alloc((size_t)NC*128*2);
  int useT = (off + (size_t)NB*NN*NC*4 <= ws_size) ? 1 : 0;
  float* featT = (float*)(useT ? alloc((size_t)NB*NN*NC*4) : (void*)ws);

  k_prep<<<512, 256, 0, stream>>>(ipw, opw, fc1w, fc2w, pe2w, bng, bnb, bnm, bnv,
                                  ipwb, opwb, fc1wb, fc2wb, pe2wb, bnsc, bnsh,
                                  first, rdy, ctl);
  if (useT)
    k_featT<<<dim3(NN/32, NB), 256, 0, stream>>>(feat, featT);

  const float* featT_c = featT;
  void* kargs[] = {
    (void*)&xyz, (void*)&feat, (void*)&featT_c, (void*)&useT,
    (void*)&cx2, (void*)&rdy, (void*)&first, (void*)&ctl,
    (void*)&pe1w, (void*)&pe1b, (void*)&bnsc, (void*)&bnsh,
    (void*)&pe2wb, (void*)&pe2b, (void*)&ipwb, (void*)&ipb,
    (void*)&opwb, (void*)&opb, (void*)&ln1s, (void*)&ln1b,
    (void*)&ln2s, (void*)&ln2b, (void*)&fc1wb, (void*)&fc1b,
    (void*)&fc2wb, (void*)&fc2b, (void*)&out };
  hipLaunchCooperativeKernel((void*)k_mega, dim3(NBLK), dim3(NTHR), kargs, 0, stream);

  if (useT)
    k_outfill_T<<<(NB*NN)/8, 256, 0, stream>>>(featT, first, out);
  else
    k_outfill_noT<<<dim3(NN/32, NB), 256, 0, stream>>>(feat, first, out);
  (void)in_sizes; (void)n_in; (void)out_size;
}